// Round 1
// baseline (614.013 us; speedup 1.0000x reference)
//
#include <hip/hip_runtime.h>

#define DIM  1024
#define HID  2048
#define OUTD 1024
#define NE   8
#define NTOK 4096

using bf16x8 = __attribute__((ext_vector_type(8))) short;
using f32x4  = __attribute__((ext_vector_type(4))) float;

__device__ __forceinline__ unsigned short f2bf(float f) {
  unsigned int u = __builtin_bit_cast(unsigned int, f);
  u += 0x7fff + ((u >> 16) & 1);   // round-to-nearest-even
  return (unsigned short)(u >> 16);
}

__device__ __forceinline__ void gload16(const void* g, void* l) {
  __builtin_amdgcn_global_load_lds(
      (const __attribute__((address_space(1))) void*)g,
      (__attribute__((address_space(3))) void*)l, 16, 0, 0);
}

// ---------------- cast X fp32 -> bf16 ----------------
__global__ void cast_x_kernel(const float* __restrict__ in,
                              unsigned short* __restrict__ out, int n8) {
  int i = blockIdx.x * blockDim.x + threadIdx.x;
  if (i >= n8) return;
  const float4* p = (const float4*)(in + (size_t)i * 8);
  float4 a = p[0], b = p[1];
  ushort4 u0, u1;
  u0.x = f2bf(a.x); u0.y = f2bf(a.y); u0.z = f2bf(a.z); u0.w = f2bf(a.w);
  u1.x = f2bf(b.x); u1.y = f2bf(b.y); u1.z = f2bf(b.z); u1.w = f2bf(b.w);
  *(ushort4*)(out + (size_t)i * 8)     = u0;
  *(ushort4*)(out + (size_t)i * 8 + 4) = u1;
}

// ---------------- transpose + cast: in [R][C] fp32 -> out [C][R] bf16 ----------------
__global__ void tcast_kernel(const float* __restrict__ in,
                             unsigned short* __restrict__ out, int R, int C) {
  __shared__ float tile[32][33];
  size_t zo = (size_t)blockIdx.z * R * C;
  int c0 = blockIdx.x * 32, r0 = blockIdx.y * 32;
  int tx = threadIdx.x & 31, ty = threadIdx.x >> 5;  // tx 0..31, ty 0..7
#pragma unroll
  for (int j = 0; j < 4; j++) {
    int r = ty + j * 8;
    tile[r][tx] = in[zo + (size_t)(r0 + r) * C + c0 + tx];
  }
  __syncthreads();
#pragma unroll
  for (int j = 0; j < 4; j++) {
    int c = ty + j * 8;
    out[zo + (size_t)(c0 + c) * R + r0 + tx] = f2bf(tile[tx][c]);
  }
}

// ---------------- gating: fp32 logits, softmax, top-2, counts ----------------
__global__ void gating_kernel(const float* __restrict__ X, const float* __restrict__ Wg,
                              const float* __restrict__ bg, int* __restrict__ topk_idx,
                              float* __restrict__ topk_w, int* __restrict__ counts) {
  int t = blockIdx.x, lane = threadIdx.x;
  float acc[NE];
#pragma unroll
  for (int e = 0; e < NE; e++) acc[e] = 0.f;
  for (int d = lane; d < DIM; d += 64) {
    float xv = X[(size_t)t * DIM + d];
#pragma unroll
    for (int e = 0; e < NE; e++) acc[e] += xv * Wg[d * NE + e];
  }
#pragma unroll
  for (int e = 0; e < NE; e++) {
#pragma unroll
    for (int off = 32; off > 0; off >>= 1) acc[e] += __shfl_xor(acc[e], off, 64);
  }
  if (lane == 0) {
    float p[NE];
    float mx = -1e30f;
#pragma unroll
    for (int e = 0; e < NE; e++) { p[e] = acc[e] + bg[e]; mx = fmaxf(mx, p[e]); }
    float s = 0.f;
#pragma unroll
    for (int e = 0; e < NE; e++) { p[e] = expf(p[e] - mx); s += p[e]; }
    float inv = 1.f / s;
#pragma unroll
    for (int e = 0; e < NE; e++) p[e] *= inv;
    // top-2 matching ascending stable argsort take-last-2 (ties -> larger index)
    int i1 = 0; float v1 = p[0];
#pragma unroll
    for (int e = 1; e < NE; e++) if (p[e] >= v1) { v1 = p[e]; i1 = e; }
    int i2 = (i1 == 0) ? 1 : 0; float v2 = p[i2];
#pragma unroll
    for (int e = 0; e < NE; e++) {
      if (e == i1) continue;
      if (p[e] >= v2 && e != i2) { v2 = p[e]; i2 = e; }
    }
    topk_idx[t * 2 + 0] = i1; topk_idx[t * 2 + 1] = i2;
    topk_w[t * 2 + 0] = v1;  topk_w[t * 2 + 1] = v2;
    atomicAdd(&counts[i1], 1); atomicAdd(&counts[i2], 1);
  }
}

__global__ void finalize_kernel(const int* __restrict__ counts, int* __restrict__ row_start) {
  if (threadIdx.x == 0) {
    int s = 0;
#pragma unroll
    for (int e = 0; e < NE; e++) { row_start[e] = s; s += counts[e]; }
  }
}

__global__ void scatter_kernel(const int* __restrict__ topk_idx, const int* __restrict__ row_start,
                               int* __restrict__ cursors, int* __restrict__ list) {
  int t = blockIdx.x * blockDim.x + threadIdx.x;
  if (t >= NTOK) return;
#pragma unroll
  for (int s = 0; s < 2; s++) {
    int e = topk_idx[t * 2 + s];
    int pos = atomicAdd(&cursors[e], 1);
    list[row_start[e] + pos] = (t << 1) | s;
  }
}

// ---------------- stage A: h = silu((Xg@W1+b1)*(Xg@W3+b3)), grouped ----------------
__global__ __launch_bounds__(256) void ffn_a_kernel(
    const unsigned short* __restrict__ Xb,
    const unsigned short* __restrict__ W1t,  // [NE][HID][DIM] bf16
    const unsigned short* __restrict__ W3t,
    const float* __restrict__ b1, const float* __restrict__ b3,
    const int* __restrict__ counts, const int* __restrict__ row_start,
    const int* __restrict__ list, unsigned short* __restrict__ h_buf) {
  const int e = blockIdx.z;
  const int ne = counts[e];
  const int m0 = blockIdx.y * 128;
  if (m0 >= ne) return;
  const int n0 = blockIdx.x * 128;
  const int rs = row_start[e];

  __shared__ unsigned short As[128 * 64];
  __shared__ unsigned short B1s[128 * 64];
  __shared__ unsigned short B3s[128 * 64];

  const int tid = threadIdx.x;
  const int wave = tid >> 6, lane = tid & 63;
  const int lrow = lane >> 3;
  const int lcol = (lane & 7) * 8;

  const unsigned short* asrc[4];
  const unsigned short* b1src[4];
  const unsigned short* b3src[4];
#pragma unroll
  for (int i = 0; i < 4; i++) {
    int sr = (wave * 4 + i) * 8 + lrow;            // staging row 0..127
    int rr = m0 + sr; if (rr >= ne) rr = m0;       // clamp to a valid row
    int tok = list[rs + rr] >> 1;
    asrc[i]  = Xb  + (size_t)tok * DIM + lcol;
    b1src[i] = W1t + ((size_t)e * HID + n0 + sr) * DIM + lcol;
    b3src[i] = W3t + ((size_t)e * HID + n0 + sr) * DIM + lcol;
  }

  const int wm = (wave >> 1) * 64, wn = (wave & 1) * 64;
  const int lr = lane & 15, lk = lane >> 4;

  f32x4 acc1[4][4], acc3[4][4];
  const f32x4 zero = {0.f, 0.f, 0.f, 0.f};
#pragma unroll
  for (int m = 0; m < 4; m++)
#pragma unroll
    for (int n = 0; n < 4; n++) { acc1[m][n] = zero; acc3[m][n] = zero; }

  for (int k0 = 0; k0 < DIM; k0 += 64) {
#pragma unroll
    for (int i = 0; i < 4; i++) {
      gload16(asrc[i]  + k0, &As [(wave * 4 + i) * 512]);
      gload16(b1src[i] + k0, &B1s[(wave * 4 + i) * 512]);
      gload16(b3src[i] + k0, &B3s[(wave * 4 + i) * 512]);
    }
    __syncthreads();
#pragma unroll
    for (int kk = 0; kk < 2; kk++) {
      bf16x8 a[4], bb1[4], bb3[4];
#pragma unroll
      for (int m = 0; m < 4; m++)
        a[m] = *(const bf16x8*)&As[(wm + m * 16 + lr) * 64 + kk * 32 + lk * 8];
#pragma unroll
      for (int n = 0; n < 4; n++) {
        bb1[n] = *(const bf16x8*)&B1s[(wn + n * 16 + lr) * 64 + kk * 32 + lk * 8];
        bb3[n] = *(const bf16x8*)&B3s[(wn + n * 16 + lr) * 64 + kk * 32 + lk * 8];
      }
#pragma unroll
      for (int m = 0; m < 4; m++)
#pragma unroll
        for (int n = 0; n < 4; n++) {
          acc1[m][n] = __builtin_amdgcn_mfma_f32_16x16x32_bf16(a[m], bb1[n], acc1[m][n], 0, 0, 0);
          acc3[m][n] = __builtin_amdgcn_mfma_f32_16x16x32_bf16(a[m], bb3[n], acc3[m][n], 0, 0, 0);
        }
    }
    __syncthreads();
  }

#pragma unroll
  for (int n = 0; n < 4; n++) {
    int col = n0 + wn + n * 16 + lr;
    float b1v = b1[e * HID + col];
    float b3v = b3[e * HID + col];
#pragma unroll
    for (int m = 0; m < 4; m++) {
#pragma unroll
      for (int j = 0; j < 4; j++) {
        int rr = m0 + wm + m * 16 + lk * 4 + j;
        if (rr < ne) {
          float h1 = acc1[m][n][j] + b1v;
          float h3 = acc3[m][n][j] + b3v;
          float g = h1 * h3;
          float h = g / (1.f + expf(-g));   // silu(h1*h3)
          h_buf[(size_t)(rs + rr) * HID + col] = f2bf(h);
        }
      }
    }
  }
}

// ---------------- stage B: o = w * (h@W2 + b2), scatter to o_buf[t][slot] ----------------
__global__ __launch_bounds__(256) void ffn_b_kernel(
    const unsigned short* __restrict__ h_buf,
    const unsigned short* __restrict__ W2t,  // [NE][OUTD][HID] bf16
    const float* __restrict__ b2,
    const int* __restrict__ counts, const int* __restrict__ row_start,
    const int* __restrict__ list, const float* __restrict__ topk_w,
    float* __restrict__ o_buf) {
  const int e = blockIdx.z;
  const int ne = counts[e];
  const int m0 = blockIdx.y * 128;
  if (m0 >= ne) return;
  const int n0 = blockIdx.x * 128;
  const int rs = row_start[e];

  __shared__ unsigned short As[128 * 64];
  __shared__ unsigned short Bs[128 * 64];

  const int tid = threadIdx.x;
  const int wave = tid >> 6, lane = tid & 63;
  const int lrow = lane >> 3;
  const int lcol = (lane & 7) * 8;

  const unsigned short* asrc[4];
  const unsigned short* bsrc[4];
#pragma unroll
  for (int i = 0; i < 4; i++) {
    int sr = (wave * 4 + i) * 8 + lrow;
    asrc[i] = h_buf + (size_t)(rs + m0 + sr) * HID + lcol;   // contiguous rows (padded)
    bsrc[i] = W2t + ((size_t)e * OUTD + n0 + sr) * HID + lcol;
  }

  const int wm = (wave >> 1) * 64, wn = (wave & 1) * 64;
  const int lr = lane & 15, lk = lane >> 4;

  f32x4 acc[4][4];
  const f32x4 zero = {0.f, 0.f, 0.f, 0.f};
#pragma unroll
  for (int m = 0; m < 4; m++)
#pragma unroll
    for (int n = 0; n < 4; n++) acc[m][n] = zero;

  for (int k0 = 0; k0 < HID; k0 += 64) {
#pragma unroll
    for (int i = 0; i < 4; i++) {
      gload16(asrc[i] + k0, &As[(wave * 4 + i) * 512]);
      gload16(bsrc[i] + k0, &Bs[(wave * 4 + i) * 512]);
    }
    __syncthreads();
#pragma unroll
    for (int kk = 0; kk < 2; kk++) {
      bf16x8 a[4], b[4];
#pragma unroll
      for (int m = 0; m < 4; m++)
        a[m] = *(const bf16x8*)&As[(wm + m * 16 + lr) * 64 + kk * 32 + lk * 8];
#pragma unroll
      for (int n = 0; n < 4; n++)
        b[n] = *(const bf16x8*)&Bs[(wn + n * 16 + lr) * 64 + kk * 32 + lk * 8];
#pragma unroll
      for (int m = 0; m < 4; m++)
#pragma unroll
        for (int n = 0; n < 4; n++)
          acc[m][n] = __builtin_amdgcn_mfma_f32_16x16x32_bf16(a[m], b[n], acc[m][n], 0, 0, 0);
    }
    __syncthreads();
  }

#pragma unroll
  for (int n = 0; n < 4; n++) {
    int col = n0 + wn + n * 16 + lr;
    float b2v = b2[e * OUTD + col];
#pragma unroll
    for (int m = 0; m < 4; m++) {
#pragma unroll
      for (int j = 0; j < 4; j++) {
        int rr = m0 + wm + m * 16 + lk * 4 + j;
        if (rr < ne) {
          int entry = list[rs + rr];           // (t<<1)|slot
          float w = topk_w[entry];
          o_buf[(size_t)entry * OUTD + col] = w * (acc[m][n][j] + b2v);
        }
      }
    }
  }
}

// ---------------- final: out = (o0 + o1) @ Wf + bf ----------------
__global__ __launch_bounds__(256) void final_kernel(
    const float* __restrict__ o_buf, const unsigned short* __restrict__ Wft,
    const float* __restrict__ bfv, float* __restrict__ out) {
  const int m0 = blockIdx.y * 128, n0 = blockIdx.x * 128;

  __shared__ unsigned short As[128 * 64];
  __shared__ unsigned short Bs[128 * 64];

  const int tid = threadIdx.x;
  const int wave = tid >> 6, lane = tid & 63;
  const int lrow = lane >> 3;
  const int lcol = (lane & 7) * 8;

  const unsigned short* bsrc[4];
#pragma unroll
  for (int i = 0; i < 4; i++) {
    int sr = (wave * 4 + i) * 8 + lrow;
    bsrc[i] = Wft + (size_t)(n0 + sr) * DIM + lcol;
  }

  const int wm = (wave >> 1) * 64, wn = (wave & 1) * 64;
  const int lr = lane & 15, lk = lane >> 4;

  f32x4 acc[4][4];
  const f32x4 zero = {0.f, 0.f, 0.f, 0.f};
#pragma unroll
  for (int m = 0; m < 4; m++)
#pragma unroll
    for (int n = 0; n < 4; n++) acc[m][n] = zero;

  for (int k0 = 0; k0 < DIM; k0 += 64) {
    // A staging: combine the two weighted slot outputs, cast to bf16
#pragma unroll
    for (int g = 0; g < 8; g++) {
      int idx = g * 256 + tid;       // 0..2047
      int r = idx >> 4;              // 0..127
      int c4 = (idx & 15) * 4;       // 0..60
      const float4 v0 = *(const float4*)&o_buf[(size_t)(m0 + r) * 2 * OUTD + k0 + c4];
      const float4 v1 = *(const float4*)&o_buf[(size_t)(m0 + r) * 2 * OUTD + OUTD + k0 + c4];
      ushort4 u;
      u.x = f2bf(v0.x + v1.x); u.y = f2bf(v0.y + v1.y);
      u.z = f2bf(v0.z + v1.z); u.w = f2bf(v0.w + v1.w);
      *(ushort4*)&As[r * 64 + c4] = u;
    }
#pragma unroll
    for (int i = 0; i < 4; i++) gload16(bsrc[i] + k0, &Bs[(wave * 4 + i) * 512]);
    __syncthreads();
#pragma unroll
    for (int kk = 0; kk < 2; kk++) {
      bf16x8 a[4], b[4];
#pragma unroll
      for (int m = 0; m < 4; m++)
        a[m] = *(const bf16x8*)&As[(wm + m * 16 + lr) * 64 + kk * 32 + lk * 8];
#pragma unroll
      for (int n = 0; n < 4; n++)
        b[n] = *(const bf16x8*)&Bs[(wn + n * 16 + lr) * 64 + kk * 32 + lk * 8];
#pragma unroll
      for (int m = 0; m < 4; m++)
#pragma unroll
        for (int n = 0; n < 4; n++)
          acc[m][n] = __builtin_amdgcn_mfma_f32_16x16x32_bf16(a[m], b[n], acc[m][n], 0, 0, 0);
    }
    __syncthreads();
  }

#pragma unroll
  for (int n = 0; n < 4; n++) {
    int col = n0 + wn + n * 16 + lr;
    float bv = bfv[col];
#pragma unroll
    for (int m = 0; m < 4; m++) {
#pragma unroll
      for (int j = 0; j < 4; j++) {
        int r = m0 + wm + m * 16 + lk * 4 + j;
        out[(size_t)r * OUTD + col] = acc[m][n][j] + bv;
      }
    }
  }
}

extern "C" void kernel_launch(void* const* d_in, const int* in_sizes, int n_in,
                              void* d_out, int out_size, void* d_ws, size_t ws_size,
                              hipStream_t stream) {
  const float* X   = (const float*)d_in[0];
  const float* W1  = (const float*)d_in[1];
  const float* b1  = (const float*)d_in[2];
  const float* W3  = (const float*)d_in[3];
  const float* b3  = (const float*)d_in[4];
  const float* W2  = (const float*)d_in[5];
  const float* b2  = (const float*)d_in[6];
  const float* Wg  = (const float*)d_in[7];
  const float* bg  = (const float*)d_in[8];
  const float* Wf  = (const float*)d_in[9];
  const float* bfv = (const float*)d_in[10];
  float* out = (float*)d_out;

  char* p = (char*)d_ws;
  auto alloc = [&](size_t bytes) { char* r = p; p += (bytes + 255) & ~(size_t)255; return r; };
  unsigned short* Xb   = (unsigned short*)alloc((size_t)NTOK * DIM * 2);
  unsigned short* W1t  = (unsigned short*)alloc((size_t)NE * HID * DIM * 2);
  unsigned short* W3t  = (unsigned short*)alloc((size_t)NE * HID * DIM * 2);
  unsigned short* W2t  = (unsigned short*)alloc((size_t)NE * OUTD * HID * 2);
  unsigned short* Wft  = (unsigned short*)alloc((size_t)OUTD * DIM * 2);
  unsigned short* hbuf = (unsigned short*)alloc((size_t)(NTOK * 2 + 128) * HID * 2);
  float* o_buf         = (float*)alloc((size_t)NTOK * 2 * OUTD * 4);
  int* topk_idx        = (int*)alloc(NTOK * 2 * 4);
  float* topk_w        = (float*)alloc(NTOK * 2 * 4);
  int* counts          = (int*)alloc(2 * NE * 4);
  int* cursors         = counts + NE;
  int* row_start       = (int*)alloc(NE * 4);
  int* list            = (int*)alloc(NTOK * 2 * 4);

  hipMemsetAsync(counts, 0, 2 * NE * sizeof(int), stream);

  cast_x_kernel<<<(NTOK * DIM / 8 + 255) / 256, 256, 0, stream>>>(X, Xb, NTOK * DIM / 8);
  tcast_kernel<<<dim3(HID / 32, DIM / 32, NE), 256, 0, stream>>>(W1, W1t, DIM, HID);
  tcast_kernel<<<dim3(HID / 32, DIM / 32, NE), 256, 0, stream>>>(W3, W3t, DIM, HID);
  tcast_kernel<<<dim3(OUTD / 32, HID / 32, NE), 256, 0, stream>>>(W2, W2t, HID, OUTD);
  tcast_kernel<<<dim3(OUTD / 32, DIM / 32, 1), 256, 0, stream>>>(Wf, Wft, DIM, OUTD);

  gating_kernel<<<NTOK, 64, 0, stream>>>(X, Wg, bg, topk_idx, topk_w, counts);
  finalize_kernel<<<1, 64, 0, stream>>>(counts, row_start);
  scatter_kernel<<<NTOK / 256, 256, 0, stream>>>(topk_idx, row_start, cursors, list);

  ffn_a_kernel<<<dim3(HID / 128, 32, NE), 256, 0, stream>>>(
      Xb, W1t, W3t, b1, b3, counts, row_start, list, hbuf);
  ffn_b_kernel<<<dim3(OUTD / 128, 32, NE), 256, 0, stream>>>(
      hbuf, W2t, b2, counts, row_start, list, topk_w, o_buf);
  final_kernel<<<dim3(OUTD / 128, NTOK / 128), 256, 0, stream>>>(o_buf, Wft, bfv, out);
}

// Round 2
// 504.356 us; speedup vs baseline: 1.2174x; 1.2174x over previous
//
#include <hip/hip_runtime.h>

#define DIM  1024
#define HID  2048
#define OUTD 1024
#define NE   8
#define NTOK 4096

using bf16x8 = __attribute__((ext_vector_type(8))) short;
using f32x4  = __attribute__((ext_vector_type(4))) float;

__device__ __forceinline__ unsigned short f2bf(float f) {
  unsigned int u = __builtin_bit_cast(unsigned int, f);
  u += 0x7fff + ((u >> 16) & 1);   // round-to-nearest-even
  return (unsigned short)(u >> 16);
}

__device__ __forceinline__ void gload16(const void* g, void* l) {
  __builtin_amdgcn_global_load_lds(
      (const __attribute__((address_space(1))) void*)g,
      (__attribute__((address_space(3))) void*)l, 16, 0, 0);
}

// ---------------- cast X fp32 -> bf16 ----------------
__global__ void cast_x_kernel(const float* __restrict__ in,
                              unsigned short* __restrict__ out, int n8) {
  int i = blockIdx.x * blockDim.x + threadIdx.x;
  if (i >= n8) return;
  const float4* p = (const float4*)(in + (size_t)i * 8);
  float4 a = p[0], b = p[1];
  ushort4 u0, u1;
  u0.x = f2bf(a.x); u0.y = f2bf(a.y); u0.z = f2bf(a.z); u0.w = f2bf(a.w);
  u1.x = f2bf(b.x); u1.y = f2bf(b.y); u1.z = f2bf(b.z); u1.w = f2bf(b.w);
  *(ushort4*)(out + (size_t)i * 8)     = u0;
  *(ushort4*)(out + (size_t)i * 8 + 4) = u1;
}

// ---------------- transpose + cast: in [R][C] fp32 -> out [C][R] bf16 ----------------
__global__ void tcast_kernel(const float* __restrict__ in,
                             unsigned short* __restrict__ out, int R, int C) {
  __shared__ float tile[32][33];
  size_t zo = (size_t)blockIdx.z * R * C;
  int c0 = blockIdx.x * 32, r0 = blockIdx.y * 32;
  int tx = threadIdx.x & 31, ty = threadIdx.x >> 5;
#pragma unroll
  for (int j = 0; j < 4; j++) {
    int r = ty + j * 8;
    tile[r][tx] = in[zo + (size_t)(r0 + r) * C + c0 + tx];
  }
  __syncthreads();
#pragma unroll
  for (int j = 0; j < 4; j++) {
    int c = ty + j * 8;
    out[zo + (size_t)(c0 + c) * R + r0 + tx] = f2bf(tile[tx][c]);
  }
}

// ---- transpose+cast W1/W3 [NE][DIM][HID] into interleaved W13t [NE][2*HID][DIM]
// out_row for hidden col h: 32*(h>>4) + 16*s + (h&15)   (16-col group interleave)
__global__ void tcast_i_kernel(const float* __restrict__ in,
                               unsigned short* __restrict__ out, int s) {
  __shared__ float tile[32][33];
  int e = blockIdx.z;
  const float* inp = in + (size_t)e * DIM * HID;
  unsigned short* op = out + (size_t)e * 2 * HID * DIM;
  int c0 = blockIdx.x * 32, r0 = blockIdx.y * 32;
  int tx = threadIdx.x & 31, ty = threadIdx.x >> 5;
#pragma unroll
  for (int j = 0; j < 4; j++) {
    int r = ty + j * 8;
    tile[r][tx] = inp[(size_t)(r0 + r) * HID + c0 + tx];
  }
  __syncthreads();
#pragma unroll
  for (int j = 0; j < 4; j++) {
    int c = ty + j * 8;
    int h = c0 + c;
    int orow = 32 * (h >> 4) + 16 * s + (h & 15);
    op[(size_t)orow * DIM + r0 + tx] = f2bf(tile[tx][c]);
  }
}

// ---------------- gating: fp32 logits, softmax, top-2, counts ----------------
__global__ void gating_kernel(const float* __restrict__ X, const float* __restrict__ Wg,
                              const float* __restrict__ bg, int* __restrict__ topk_idx,
                              float* __restrict__ topk_w, int* __restrict__ counts) {
  int t = blockIdx.x, lane = threadIdx.x;
  float acc[NE];
#pragma unroll
  for (int e = 0; e < NE; e++) acc[e] = 0.f;
  for (int d = lane; d < DIM; d += 64) {
    float xv = X[(size_t)t * DIM + d];
#pragma unroll
    for (int e = 0; e < NE; e++) acc[e] += xv * Wg[d * NE + e];
  }
#pragma unroll
  for (int e = 0; e < NE; e++) {
#pragma unroll
    for (int off = 32; off > 0; off >>= 1) acc[e] += __shfl_xor(acc[e], off, 64);
  }
  if (lane == 0) {
    float p[NE];
    float mx = -1e30f;
#pragma unroll
    for (int e = 0; e < NE; e++) { p[e] = acc[e] + bg[e]; mx = fmaxf(mx, p[e]); }
    float s = 0.f;
#pragma unroll
    for (int e = 0; e < NE; e++) { p[e] = expf(p[e] - mx); s += p[e]; }
    float inv = 1.f / s;
#pragma unroll
    for (int e = 0; e < NE; e++) p[e] *= inv;
    int i1 = 0; float v1 = p[0];
#pragma unroll
    for (int e = 1; e < NE; e++) if (p[e] >= v1) { v1 = p[e]; i1 = e; }
    int i2 = (i1 == 0) ? 1 : 0; float v2 = p[i2];
#pragma unroll
    for (int e = 0; e < NE; e++) {
      if (e == i1) continue;
      if (p[e] >= v2 && e != i2) { v2 = p[e]; i2 = e; }
    }
    topk_idx[t * 2 + 0] = i1; topk_idx[t * 2 + 1] = i2;
    topk_w[t * 2 + 0] = v1;  topk_w[t * 2 + 1] = v2;
    atomicAdd(&counts[i1], 1); atomicAdd(&counts[i2], 1);
  }
}

__global__ void finalize_kernel(const int* __restrict__ counts, int* __restrict__ row_start) {
  if (threadIdx.x == 0) {
    int s = 0;
#pragma unroll
    for (int e = 0; e < NE; e++) { row_start[e] = s; s += counts[e]; }
  }
}

__global__ void scatter_kernel(const int* __restrict__ topk_idx, const int* __restrict__ row_start,
                               int* __restrict__ cursors, int* __restrict__ list) {
  int t = blockIdx.x * blockDim.x + threadIdx.x;
  if (t >= NTOK) return;
#pragma unroll
  for (int s = 0; s < 2; s++) {
    int e = topk_idx[t * 2 + s];
    int pos = atomicAdd(&cursors[e], 1);
    list[row_start[e] + pos] = (t << 1) | s;
  }
}

// ---------------- stage A: 256x256 grouped GEMM over interleaved W13, SwiGLU epilogue
__global__ __launch_bounds__(512, 2) void ffn_a_kernel(
    const unsigned short* __restrict__ Xb,
    const unsigned short* __restrict__ W13t,  // [NE][2*HID][DIM] bf16, 16-col interleave
    const float* __restrict__ b1, const float* __restrict__ b3,
    const int* __restrict__ counts, const int* __restrict__ row_start,
    const int* __restrict__ list, unsigned short* __restrict__ h_buf) {
  extern __shared__ unsigned short lds[];   // 2 halves x (A 16384 + B 16384) elems = 128KB
  const int e = blockIdx.z;
  const int ne = counts[e];
  const int m0 = blockIdx.y * 256;
  if (m0 >= ne) return;
  const int n0 = blockIdx.x * 256;          // interleaved col space [0,4096)
  const int rs = row_start[e];

  const int tid = threadIdx.x;
  const int wave = tid >> 6, lane = tid & 63;
  const int lrow = lane >> 3, lcol = (lane & 7) * 8;

  const unsigned short* asrc[4];
  const unsigned short* bsrc[4];
#pragma unroll
  for (int i = 0; i < 4; i++) {
    int sr = (wave * 4 + i) * 8 + lrow;     // 0..255
    int rr = m0 + sr; if (rr >= ne) rr = m0;
    int tok = list[rs + rr] >> 1;
    asrc[i] = Xb + (size_t)tok * DIM + lcol;
    bsrc[i] = W13t + ((size_t)e * 2 * HID + n0 + sr) * DIM + lcol;
  }

  const int wm = (wave >> 2) * 128, wn = (wave & 3) * 64;
  const int lr = lane & 15, lk = lane >> 4;

  f32x4 acc[8][4];
  const f32x4 zero = {0.f, 0.f, 0.f, 0.f};
#pragma unroll
  for (int m = 0; m < 8; m++)
#pragma unroll
    for (int n = 0; n < 4; n++) acc[m][n] = zero;

  auto STAGE = [&](int half, int k0) {
    unsigned short* A = lds + half * 32768;
    unsigned short* B = A + 16384;
#pragma unroll
    for (int i = 0; i < 4; i++) {
      gload16(asrc[i] + k0, A + (wave * 4 + i) * 512);
      gload16(bsrc[i] + k0, B + (wave * 4 + i) * 512);
    }
  };

  STAGE(0, 0);
  asm volatile("s_waitcnt vmcnt(0)" ::: "memory");
  __builtin_amdgcn_s_barrier();
  asm volatile("" ::: "memory");

  int half = 0;
  const int NT = DIM / 64;
  for (int t = 0; t < NT; ++t) {
    if (t + 1 < NT) STAGE(half ^ 1, (t + 1) * 64);
    const unsigned short* A = lds + half * 32768;
    const unsigned short* B = A + 16384;
#pragma unroll
    for (int kk = 0; kk < 2; kk++) {
      bf16x8 a[8], b[4];
#pragma unroll
      for (int m = 0; m < 8; m++)
        a[m] = *(const bf16x8*)&A[(wm + m * 16 + lr) * 64 + kk * 32 + lk * 8];
#pragma unroll
      for (int n = 0; n < 4; n++)
        b[n] = *(const bf16x8*)&B[(wn + n * 16 + lr) * 64 + kk * 32 + lk * 8];
#pragma unroll
      for (int m = 0; m < 8; m++)
#pragma unroll
        for (int n = 0; n < 4; n++)
          acc[m][n] = __builtin_amdgcn_mfma_f32_16x16x32_bf16(a[m], b[n], acc[m][n], 0, 0, 0);
    }
    asm volatile("s_waitcnt vmcnt(0)" ::: "memory");
    __builtin_amdgcn_s_barrier();
    asm volatile("" ::: "memory");
    half ^= 1;
  }

  // SwiGLU epilogue: frag pair (2g, 2g+1) = (h1, h3) for hidden h = (n0+wn)/2 + g*16 + lr
  const int hbase = (n0 + wn) >> 1;
#pragma unroll
  for (int g = 0; g < 2; g++) {
    int h = hbase + g * 16 + lr;
    float b1v = b1[e * HID + h];
    float b3v = b3[e * HID + h];
#pragma unroll
    for (int m = 0; m < 8; m++) {
#pragma unroll
      for (int j = 0; j < 4; j++) {
        int rr = m0 + wm + m * 16 + lk * 4 + j;
        if (rr < ne) {
          float h1 = acc[m][2 * g][j] + b1v;
          float h3 = acc[m][2 * g + 1][j] + b3v;
          float v = h1 * h3;
          h_buf[(size_t)(rs + rr) * HID + h] = f2bf(v / (1.f + expf(-v)));
        }
      }
    }
  }
}

// ---------------- stage B: 128x256 grouped GEMM, gate-weighted scatter ----------------
__global__ __launch_bounds__(512, 2) void ffn_b_kernel(
    const unsigned short* __restrict__ h_buf,
    const unsigned short* __restrict__ W2t,  // [NE][OUTD][HID] bf16
    const float* __restrict__ b2,
    const int* __restrict__ counts, const int* __restrict__ row_start,
    const int* __restrict__ list, const float* __restrict__ topk_w,
    float* __restrict__ o_buf) {
  extern __shared__ unsigned short lds[];   // 2 halves x (A 8192 + B 16384) elems = 96KB
  const int e = blockIdx.z;
  const int ne = counts[e];
  const int m0 = blockIdx.y * 128;
  if (m0 >= ne) return;
  const int n0 = blockIdx.x * 256;
  const int rs = row_start[e];

  const int tid = threadIdx.x;
  const int wave = tid >> 6, lane = tid & 63;
  const int lrow = lane >> 3, lcol = (lane & 7) * 8;

  const unsigned short* asrc[2];
  const unsigned short* bsrc[4];
#pragma unroll
  for (int i = 0; i < 2; i++) {
    int sr = (wave * 2 + i) * 8 + lrow;     // 0..127
    asrc[i] = h_buf + (size_t)(rs + m0 + sr) * HID + lcol;  // padded rows, no clamp
  }
#pragma unroll
  for (int i = 0; i < 4; i++) {
    int sr = (wave * 4 + i) * 8 + lrow;     // 0..255
    bsrc[i] = W2t + ((size_t)e * OUTD + n0 + sr) * HID + lcol;
  }

  const int wm = (wave >> 2) * 64, wn = (wave & 3) * 64;
  const int lr = lane & 15, lk = lane >> 4;

  f32x4 acc[4][4];
  const f32x4 zero = {0.f, 0.f, 0.f, 0.f};
#pragma unroll
  for (int m = 0; m < 4; m++)
#pragma unroll
    for (int n = 0; n < 4; n++) acc[m][n] = zero;

  auto STAGE = [&](int half, int k0) {
    unsigned short* A = lds + half * 24576;
    unsigned short* B = A + 8192;
#pragma unroll
    for (int i = 0; i < 2; i++)
      gload16(asrc[i] + k0, A + (wave * 2 + i) * 512);
#pragma unroll
    for (int i = 0; i < 4; i++)
      gload16(bsrc[i] + k0, B + (wave * 4 + i) * 512);
  };

  STAGE(0, 0);
  asm volatile("s_waitcnt vmcnt(0)" ::: "memory");
  __builtin_amdgcn_s_barrier();
  asm volatile("" ::: "memory");

  int half = 0;
  const int NT = HID / 64;
  for (int t = 0; t < NT; ++t) {
    if (t + 1 < NT) STAGE(half ^ 1, (t + 1) * 64);
    const unsigned short* A = lds + half * 24576;
    const unsigned short* B = A + 8192;
#pragma unroll
    for (int kk = 0; kk < 2; kk++) {
      bf16x8 a[4], b[4];
#pragma unroll
      for (int m = 0; m < 4; m++)
        a[m] = *(const bf16x8*)&A[(wm + m * 16 + lr) * 64 + kk * 32 + lk * 8];
#pragma unroll
      for (int n = 0; n < 4; n++)
        b[n] = *(const bf16x8*)&B[(wn + n * 16 + lr) * 64 + kk * 32 + lk * 8];
#pragma unroll
      for (int m = 0; m < 4; m++)
#pragma unroll
        for (int n = 0; n < 4; n++)
          acc[m][n] = __builtin_amdgcn_mfma_f32_16x16x32_bf16(a[m], b[n], acc[m][n], 0, 0, 0);
    }
    asm volatile("s_waitcnt vmcnt(0)" ::: "memory");
    __builtin_amdgcn_s_barrier();
    asm volatile("" ::: "memory");
    half ^= 1;
  }

#pragma unroll
  for (int n = 0; n < 4; n++) {
    int col = n0 + wn + n * 16 + lr;
    float b2v = b2[e * OUTD + col];
#pragma unroll
    for (int m = 0; m < 4; m++) {
#pragma unroll
      for (int j = 0; j < 4; j++) {
        int rr = m0 + wm + m * 16 + lk * 4 + j;
        if (rr < ne) {
          int entry = list[rs + rr];
          float w = topk_w[entry];
          o_buf[(size_t)entry * OUTD + col] = w * (acc[m][n][j] + b2v);
        }
      }
    }
  }
}

// ---------------- final: out = (o0 + o1) @ Wf + bf ----------------
__global__ __launch_bounds__(256) void final_kernel(
    const float* __restrict__ o_buf, const unsigned short* __restrict__ Wft,
    const float* __restrict__ bfv, float* __restrict__ out) {
  const int m0 = blockIdx.y * 128, n0 = blockIdx.x * 128;

  __shared__ unsigned short As[128 * 64];
  __shared__ unsigned short Bs[128 * 64];

  const int tid = threadIdx.x;
  const int wave = tid >> 6, lane = tid & 63;
  const int lrow = lane >> 3;
  const int lcol = (lane & 7) * 8;

  const unsigned short* bsrc[4];
#pragma unroll
  for (int i = 0; i < 4; i++) {
    int sr = (wave * 4 + i) * 8 + lrow;
    bsrc[i] = Wft + (size_t)(n0 + sr) * DIM + lcol;
  }

  const int wm = (wave >> 1) * 64, wn = (wave & 1) * 64;
  const int lr = lane & 15, lk = lane >> 4;

  f32x4 acc[4][4];
  const f32x4 zero = {0.f, 0.f, 0.f, 0.f};
#pragma unroll
  for (int m = 0; m < 4; m++)
#pragma unroll
    for (int n = 0; n < 4; n++) acc[m][n] = zero;

  for (int k0 = 0; k0 < DIM; k0 += 64) {
#pragma unroll
    for (int g = 0; g < 8; g++) {
      int idx = g * 256 + tid;
      int r = idx >> 4;
      int c4 = (idx & 15) * 4;
      const float4 v0 = *(const float4*)&o_buf[(size_t)(m0 + r) * 2 * OUTD + k0 + c4];
      const float4 v1 = *(const float4*)&o_buf[(size_t)(m0 + r) * 2 * OUTD + OUTD + k0 + c4];
      ushort4 u;
      u.x = f2bf(v0.x + v1.x); u.y = f2bf(v0.y + v1.y);
      u.z = f2bf(v0.z + v1.z); u.w = f2bf(v0.w + v1.w);
      *(ushort4*)&As[r * 64 + c4] = u;
    }
#pragma unroll
    for (int i = 0; i < 4; i++) gload16(bsrc[i] + k0, &Bs[(wave * 4 + i) * 512]);
    __syncthreads();
#pragma unroll
    for (int kk = 0; kk < 2; kk++) {
      bf16x8 a[4], b[4];
#pragma unroll
      for (int m = 0; m < 4; m++)
        a[m] = *(const bf16x8*)&As[(wm + m * 16 + lr) * 64 + kk * 32 + lk * 8];
#pragma unroll
      for (int n = 0; n < 4; n++)
        b[n] = *(const bf16x8*)&Bs[(wn + n * 16 + lr) * 64 + kk * 32 + lk * 8];
#pragma unroll
      for (int m = 0; m < 4; m++)
#pragma unroll
        for (int n = 0; n < 4; n++)
          acc[m][n] = __builtin_amdgcn_mfma_f32_16x16x32_bf16(a[m], b[n], acc[m][n], 0, 0, 0);
    }
    __syncthreads();
  }

#pragma unroll
  for (int n = 0; n < 4; n++) {
    int col = n0 + wn + n * 16 + lr;
    float bv = bfv[col];
#pragma unroll
    for (int m = 0; m < 4; m++) {
#pragma unroll
      for (int j = 0; j < 4; j++) {
        int r = m0 + wm + m * 16 + lk * 4 + j;
        out[(size_t)r * OUTD + col] = acc[m][n][j] + bv;
      }
    }
  }
}

extern "C" void kernel_launch(void* const* d_in, const int* in_sizes, int n_in,
                              void* d_out, int out_size, void* d_ws, size_t ws_size,
                              hipStream_t stream) {
  const float* X   = (const float*)d_in[0];
  const float* W1  = (const float*)d_in[1];
  const float* b1  = (const float*)d_in[2];
  const float* W3  = (const float*)d_in[3];
  const float* b3  = (const float*)d_in[4];
  const float* W2  = (const float*)d_in[5];
  const float* b2  = (const float*)d_in[6];
  const float* Wg  = (const float*)d_in[7];
  const float* bg  = (const float*)d_in[8];
  const float* Wf  = (const float*)d_in[9];
  const float* bfv = (const float*)d_in[10];
  float* out = (float*)d_out;

  char* p = (char*)d_ws;
  auto alloc = [&](size_t bytes) { char* r = p; p += (bytes + 255) & ~(size_t)255; return r; };
  unsigned short* Xb   = (unsigned short*)alloc((size_t)NTOK * DIM * 2);
  unsigned short* W13t = (unsigned short*)alloc((size_t)NE * 2 * HID * DIM * 2);
  unsigned short* W2t  = (unsigned short*)alloc((size_t)NE * OUTD * HID * 2);
  unsigned short* Wft  = (unsigned short*)alloc((size_t)OUTD * DIM * 2);
  unsigned short* hbuf = (unsigned short*)alloc((size_t)(NTOK * 2 + 256) * HID * 2);
  float* o_buf         = (float*)alloc((size_t)NTOK * 2 * OUTD * 4);
  int* topk_idx        = (int*)alloc(NTOK * 2 * 4);
  float* topk_w        = (float*)alloc(NTOK * 2 * 4);
  int* counts          = (int*)alloc(2 * NE * 4);
  int* cursors         = counts + NE;
  int* row_start       = (int*)alloc(NE * 4);
  int* list            = (int*)alloc(NTOK * 2 * 4);

  hipFuncSetAttribute((const void*)ffn_a_kernel,
                      hipFuncAttributeMaxDynamicSharedMemorySize, 131072);
  hipFuncSetAttribute((const void*)ffn_b_kernel,
                      hipFuncAttributeMaxDynamicSharedMemorySize, 98304);

  hipMemsetAsync(counts, 0, 2 * NE * sizeof(int), stream);

  cast_x_kernel<<<(NTOK * DIM / 8 + 255) / 256, 256, 0, stream>>>(X, Xb, NTOK * DIM / 8);
  tcast_i_kernel<<<dim3(HID / 32, DIM / 32, NE), 256, 0, stream>>>(W1, W13t, 0);
  tcast_i_kernel<<<dim3(HID / 32, DIM / 32, NE), 256, 0, stream>>>(W3, W13t, 1);
  tcast_kernel<<<dim3(OUTD / 32, HID / 32, NE), 256, 0, stream>>>(W2, W2t, HID, OUTD);
  tcast_kernel<<<dim3(OUTD / 32, DIM / 32, 1), 256, 0, stream>>>(Wf, Wft, DIM, OUTD);

  gating_kernel<<<NTOK, 64, 0, stream>>>(X, Wg, bg, topk_idx, topk_w, counts);
  finalize_kernel<<<1, 64, 0, stream>>>(counts, row_start);
  scatter_kernel<<<NTOK / 256, 256, 0, stream>>>(topk_idx, row_start, cursors, list);

  ffn_a_kernel<<<dim3(2 * HID / 256, 16, NE), 512, 131072, stream>>>(
      Xb, W13t, b1, b3, counts, row_start, list, hbuf);
  ffn_b_kernel<<<dim3(OUTD / 256, 32, NE), 512, 98304, stream>>>(
      hbuf, W2t, b2, counts, row_start, list, topk_w, o_buf);
  final_kernel<<<dim3(OUTD / 128, NTOK / 128), 256, 0, stream>>>(o_buf, Wft, bfv, out);
}

// Round 3
// 492.144 us; speedup vs baseline: 1.2476x; 1.0248x over previous
//
#include <hip/hip_runtime.h>

#define DIM  1024
#define HID  2048
#define OUTD 1024
#define NE   8
#define NTOK 4096

using bf16x8 = __attribute__((ext_vector_type(8))) short;
using f32x4  = __attribute__((ext_vector_type(4))) float;

__device__ __forceinline__ unsigned short f2bf(float f) {
  unsigned int u = __builtin_bit_cast(unsigned int, f);
  u += 0x7fff + ((u >> 16) & 1);   // round-to-nearest-even
  return (unsigned short)(u >> 16);
}

__device__ __forceinline__ void gload16(const void* g, void* l) {
  __builtin_amdgcn_global_load_lds(
      (const __attribute__((address_space(1))) void*)g,
      (__attribute__((address_space(3))) void*)l, 16, 0, 0);
}

// ---------------- cast X fp32 -> bf16 ----------------
__global__ void cast_x_kernel(const float* __restrict__ in,
                              unsigned short* __restrict__ out, int n8) {
  int i = blockIdx.x * blockDim.x + threadIdx.x;
  if (i >= n8) return;
  const float4* p = (const float4*)(in + (size_t)i * 8);
  float4 a = p[0], b = p[1];
  ushort4 u0, u1;
  u0.x = f2bf(a.x); u0.y = f2bf(a.y); u0.z = f2bf(a.z); u0.w = f2bf(a.w);
  u1.x = f2bf(b.x); u1.y = f2bf(b.y); u1.z = f2bf(b.z); u1.w = f2bf(b.w);
  *(ushort4*)(out + (size_t)i * 8)     = u0;
  *(ushort4*)(out + (size_t)i * 8 + 4) = u1;
}

// ---------------- transpose + cast: in [R][C] fp32 -> out [C][R] bf16 ----------------
__global__ void tcast_kernel(const float* __restrict__ in,
                             unsigned short* __restrict__ out, int R, int C) {
  __shared__ float tile[32][33];
  size_t zo = (size_t)blockIdx.z * R * C;
  int c0 = blockIdx.x * 32, r0 = blockIdx.y * 32;
  int tx = threadIdx.x & 31, ty = threadIdx.x >> 5;
#pragma unroll
  for (int j = 0; j < 4; j++) {
    int r = ty + j * 8;
    tile[r][tx] = in[zo + (size_t)(r0 + r) * C + c0 + tx];
  }
  __syncthreads();
#pragma unroll
  for (int j = 0; j < 4; j++) {
    int c = ty + j * 8;
    out[zo + (size_t)(c0 + c) * R + r0 + tx] = f2bf(tile[tx][c]);
  }
}

// ---- transpose+cast W1/W3 [NE][DIM][HID] into interleaved W13t [NE][2*HID][DIM]
__global__ void tcast_i_kernel(const float* __restrict__ in,
                               unsigned short* __restrict__ out, int s) {
  __shared__ float tile[32][33];
  int e = blockIdx.z;
  const float* inp = in + (size_t)e * DIM * HID;
  unsigned short* op = out + (size_t)e * 2 * HID * DIM;
  int c0 = blockIdx.x * 32, r0 = blockIdx.y * 32;
  int tx = threadIdx.x & 31, ty = threadIdx.x >> 5;
#pragma unroll
  for (int j = 0; j < 4; j++) {
    int r = ty + j * 8;
    tile[r][tx] = inp[(size_t)(r0 + r) * HID + c0 + tx];
  }
  __syncthreads();
#pragma unroll
  for (int j = 0; j < 4; j++) {
    int c = ty + j * 8;
    int h = c0 + c;
    int orow = 32 * (h >> 4) + 16 * s + (h & 15);
    op[(size_t)orow * DIM + r0 + tx] = f2bf(tile[tx][c]);
  }
}

// ---------------- gating: fp32 logits, softmax, top-2, counts ----------------
__global__ void gating_kernel(const float* __restrict__ X, const float* __restrict__ Wg,
                              const float* __restrict__ bg, int* __restrict__ topk_idx,
                              float* __restrict__ topk_w, int* __restrict__ counts) {
  int t = blockIdx.x, lane = threadIdx.x;
  float acc[NE];
#pragma unroll
  for (int e = 0; e < NE; e++) acc[e] = 0.f;
  for (int d = lane; d < DIM; d += 64) {
    float xv = X[(size_t)t * DIM + d];
#pragma unroll
    for (int e = 0; e < NE; e++) acc[e] += xv * Wg[d * NE + e];
  }
#pragma unroll
  for (int e = 0; e < NE; e++) {
#pragma unroll
    for (int off = 32; off > 0; off >>= 1) acc[e] += __shfl_xor(acc[e], off, 64);
  }
  if (lane == 0) {
    float p[NE];
    float mx = -1e30f;
#pragma unroll
    for (int e = 0; e < NE; e++) { p[e] = acc[e] + bg[e]; mx = fmaxf(mx, p[e]); }
    float s = 0.f;
#pragma unroll
    for (int e = 0; e < NE; e++) { p[e] = expf(p[e] - mx); s += p[e]; }
    float inv = 1.f / s;
#pragma unroll
    for (int e = 0; e < NE; e++) p[e] *= inv;
    int i1 = 0; float v1 = p[0];
#pragma unroll
    for (int e = 1; e < NE; e++) if (p[e] >= v1) { v1 = p[e]; i1 = e; }
    int i2 = (i1 == 0) ? 1 : 0; float v2 = p[i2];
#pragma unroll
    for (int e = 0; e < NE; e++) {
      if (e == i1) continue;
      if (p[e] >= v2 && e != i2) { v2 = p[e]; i2 = e; }
    }
    topk_idx[t * 2 + 0] = i1; topk_idx[t * 2 + 1] = i2;
    topk_w[t * 2 + 0] = v1;  topk_w[t * 2 + 1] = v2;
    atomicAdd(&counts[i1], 1); atomicAdd(&counts[i2], 1);
  }
}

__global__ void finalize_kernel(const int* __restrict__ counts, int* __restrict__ row_start) {
  if (threadIdx.x == 0) {
    int s = 0;
#pragma unroll
    for (int e = 0; e < NE; e++) { row_start[e] = s; s += counts[e]; }
  }
}

__global__ void scatter_kernel(const int* __restrict__ topk_idx, const int* __restrict__ row_start,
                               int* __restrict__ cursors, int* __restrict__ list) {
  int t = blockIdx.x * blockDim.x + threadIdx.x;
  if (t >= NTOK) return;
#pragma unroll
  for (int s = 0; s < 2; s++) {
    int e = topk_idx[t * 2 + s];
    int pos = atomicAdd(&cursors[e], 1);
    list[row_start[e] + pos] = (t << 1) | s;
  }
}

// ---------------- stage A: 256x256 grouped GEMM, BK=32 ring-4, T2+T4+T5 ----------------
__global__ __launch_bounds__(512, 2) void ffn_a_kernel(
    const unsigned short* __restrict__ Xb,
    const unsigned short* __restrict__ W13t,  // [NE][2*HID][DIM] bf16, 16-col interleave
    const float* __restrict__ b1, const float* __restrict__ b3,
    const int* __restrict__ counts, const int* __restrict__ row_start,
    const int* __restrict__ list, unsigned short* __restrict__ h_buf) {
  extern __shared__ unsigned short lds[];   // 4 bufs x (A 8192 + B 8192) shorts = 128KB
  const int e = blockIdx.z;
  const int ne = counts[e];
  const int m0 = blockIdx.y * 256;
  if (m0 >= ne) return;
  const int n0 = blockIdx.x * 256;
  const int rs = row_start[e];

  const int tid = threadIdx.x;
  const int wave = tid >> 6, lane = tid & 63;

  // staging geometry: chunk row = c*128 + wave*16 + (lane>>2); 16B slot = lane&3
  const int srow = wave * 16 + (lane >> 2);
  const int sslot = lane & 3;
  const unsigned short* asrc[2];
  const unsigned short* bsrc[2];
#pragma unroll
  for (int c = 0; c < 2; c++) {
    int r = c * 128 + srow;
    int rr = m0 + r; if (rr >= ne) rr = m0;
    int tok = list[rs + rr] >> 1;
    int cs = (sslot ^ ((r >> 1) & 3)) * 8;     // inverse-swizzled source column (shorts)
    asrc[c] = Xb + (size_t)tok * DIM + cs;
    bsrc[c] = W13t + ((size_t)e * 2 * HID + n0 + r) * DIM + cs;
  }

  const int wm = (wave >> 2) * 128, wn = (wave & 3) * 64;
  const int lr = lane & 15, lk = lane >> 4;

  f32x4 acc[8][4];
  const f32x4 zero = {0.f, 0.f, 0.f, 0.f};
#pragma unroll
  for (int m = 0; m < 8; m++)
#pragma unroll
    for (int n = 0; n < 4; n++) acc[m][n] = zero;

  auto STAGE = [&](int tt) {
    unsigned short* base = lds + (tt & 3) * 16384;
    const int k0 = tt * 32;
#pragma unroll
    for (int c = 0; c < 2; c++) {
      gload16(asrc[c] + k0, base + c * 4096 + wave * 512);           // wave-uniform dest
      gload16(bsrc[c] + k0, base + 8192 + c * 4096 + wave * 512);
    }
  };

  auto TILE = [&](int t, bool doStage) {
    const unsigned short* Abuf = lds + (t & 3) * 16384;
    const unsigned short* Bbuf = Abuf + 8192;
    if (doStage) STAGE(t + 3);
    bf16x8 b[4];
#pragma unroll
    for (int n = 0; n < 4; n++) {
      int rb = wn + n * 16 + lr;
      b[n] = *(const bf16x8*)&Bbuf[rb * 32 + (lk ^ ((rb >> 1) & 3)) * 8];
    }
#pragma unroll
    for (int mh = 0; mh < 2; mh++) {
      bf16x8 a[4];
#pragma unroll
      for (int mi = 0; mi < 4; mi++) {
        int ra = wm + (mh * 4 + mi) * 16 + lr;
        a[mi] = *(const bf16x8*)&Abuf[ra * 32 + (lk ^ ((ra >> 1) & 3)) * 8];
      }
      __builtin_amdgcn_s_setprio(1);
#pragma unroll
      for (int mi = 0; mi < 4; mi++)
#pragma unroll
        for (int n = 0; n < 4; n++)
          acc[mh * 4 + mi][n] =
              __builtin_amdgcn_mfma_f32_16x16x32_bf16(a[mi], b[n], acc[mh * 4 + mi][n], 0, 0, 0);
      __builtin_amdgcn_s_setprio(0);
    }
  };

  const int NT = DIM / 32;
  STAGE(0); STAGE(1); STAGE(2);
  asm volatile("s_waitcnt vmcnt(8)" ::: "memory");
  __builtin_amdgcn_s_barrier();
  asm volatile("" ::: "memory");

  int t = 0;
#pragma unroll 4
  for (; t < NT - 3; ++t) {
    TILE(t, true);
    asm volatile("s_waitcnt vmcnt(8)" ::: "memory");
    __builtin_amdgcn_s_barrier();
    asm volatile("" ::: "memory");
  }
  TILE(NT - 3, false);
  asm volatile("s_waitcnt vmcnt(4)" ::: "memory");
  __builtin_amdgcn_s_barrier();
  asm volatile("" ::: "memory");
  TILE(NT - 2, false);
  asm volatile("s_waitcnt vmcnt(0)" ::: "memory");
  __builtin_amdgcn_s_barrier();
  asm volatile("" ::: "memory");
  TILE(NT - 1, false);

  // SwiGLU epilogue: frag pair (2g, 2g+1) = (h1, h3) for hidden h = (n0+wn)/2 + g*16 + lr
  const int hbase = (n0 + wn) >> 1;
#pragma unroll
  for (int g = 0; g < 2; g++) {
    int h = hbase + g * 16 + lr;
    float b1v = b1[e * HID + h];
    float b3v = b3[e * HID + h];
#pragma unroll
    for (int m = 0; m < 8; m++) {
#pragma unroll
      for (int j = 0; j < 4; j++) {
        int rr = m0 + wm + m * 16 + lr / 16 * 0 + (lane >> 4) * 4 + j;
        if (rr < ne) {
          float h1 = acc[m][2 * g][j] + b1v;
          float h3 = acc[m][2 * g + 1][j] + b3v;
          float v = h1 * h3;
          h_buf[(size_t)(rs + rr) * HID + h] = f2bf(v / (1.f + expf(-v)));
        }
      }
    }
  }
}

// ---------------- stage B: 128x256 grouped GEMM, BK=32 ring-4, T2+T4+T5 ----------------
__global__ __launch_bounds__(512, 2) void ffn_b_kernel(
    const unsigned short* __restrict__ h_buf,
    const unsigned short* __restrict__ W2t,  // [NE][OUTD][HID] bf16
    const float* __restrict__ b2,
    const int* __restrict__ counts, const int* __restrict__ row_start,
    const int* __restrict__ list, const float* __restrict__ topk_w,
    float* __restrict__ o_buf) {
  extern __shared__ unsigned short lds[];   // 4 bufs x (A 4096 + B 8192) shorts = 96KB
  const int e = blockIdx.z;
  const int ne = counts[e];
  const int m0 = blockIdx.y * 128;
  if (m0 >= ne) return;
  const int n0 = blockIdx.x * 256;
  const int rs = row_start[e];

  const int tid = threadIdx.x;
  const int wave = tid >> 6, lane = tid & 63;

  const int srow = wave * 16 + (lane >> 2);  // 0..127
  const int sslot = lane & 3;
  const unsigned short* asrc;
  const unsigned short* bsrc[2];
  {
    int cs = (sslot ^ ((srow >> 1) & 3)) * 8;
    asrc = h_buf + (size_t)(rs + m0 + srow) * HID + cs;   // padded rows, in-bounds
  }
#pragma unroll
  for (int c = 0; c < 2; c++) {
    int r = c * 128 + srow;
    int cs = (sslot ^ ((r >> 1) & 3)) * 8;
    bsrc[c] = W2t + ((size_t)e * OUTD + n0 + r) * HID + cs;
  }

  const int wm = (wave >> 2) * 64, wn = (wave & 3) * 64;
  const int lr = lane & 15, lk = lane >> 4;

  f32x4 acc[4][4];
  const f32x4 zero = {0.f, 0.f, 0.f, 0.f};
#pragma unroll
  for (int m = 0; m < 4; m++)
#pragma unroll
    for (int n = 0; n < 4; n++) acc[m][n] = zero;

  auto STAGE = [&](int tt) {
    unsigned short* base = lds + (tt & 3) * 12288;
    const int k0 = tt * 32;
    gload16(asrc + k0, base + wave * 512);
#pragma unroll
    for (int c = 0; c < 2; c++)
      gload16(bsrc[c] + k0, base + 4096 + c * 4096 + wave * 512);
  };

  auto TILE = [&](int t, bool doStage) {
    const unsigned short* Abuf = lds + (t & 3) * 12288;
    const unsigned short* Bbuf = Abuf + 4096;
    if (doStage) STAGE(t + 3);
    bf16x8 a[4], b[4];
#pragma unroll
    for (int m = 0; m < 4; m++) {
      int ra = wm + m * 16 + lr;
      a[m] = *(const bf16x8*)&Abuf[ra * 32 + (lk ^ ((ra >> 1) & 3)) * 8];
    }
#pragma unroll
    for (int n = 0; n < 4; n++) {
      int rb = wn + n * 16 + lr;
      b[n] = *(const bf16x8*)&Bbuf[rb * 32 + (lk ^ ((rb >> 1) & 3)) * 8];
    }
    __builtin_amdgcn_s_setprio(1);
#pragma unroll
    for (int m = 0; m < 4; m++)
#pragma unroll
      for (int n = 0; n < 4; n++)
        acc[m][n] = __builtin_amdgcn_mfma_f32_16x16x32_bf16(a[m], b[n], acc[m][n], 0, 0, 0);
    __builtin_amdgcn_s_setprio(0);
  };

  const int NT = HID / 32;
  STAGE(0); STAGE(1); STAGE(2);
  asm volatile("s_waitcnt vmcnt(6)" ::: "memory");
  __builtin_amdgcn_s_barrier();
  asm volatile("" ::: "memory");

  int t = 0;
#pragma unroll 4
  for (; t < NT - 3; ++t) {
    TILE(t, true);
    asm volatile("s_waitcnt vmcnt(6)" ::: "memory");
    __builtin_amdgcn_s_barrier();
    asm volatile("" ::: "memory");
  }
  TILE(NT - 3, false);
  asm volatile("s_waitcnt vmcnt(3)" ::: "memory");
  __builtin_amdgcn_s_barrier();
  asm volatile("" ::: "memory");
  TILE(NT - 2, false);
  asm volatile("s_waitcnt vmcnt(0)" ::: "memory");
  __builtin_amdgcn_s_barrier();
  asm volatile("" ::: "memory");
  TILE(NT - 1, false);

#pragma unroll
  for (int n = 0; n < 4; n++) {
    int col = n0 + wn + n * 16 + lr;
    float b2v = b2[e * OUTD + col];
#pragma unroll
    for (int m = 0; m < 4; m++) {
#pragma unroll
      for (int j = 0; j < 4; j++) {
        int rr = m0 + wm + m * 16 + lk * 4 + j;
        if (rr < ne) {
          int entry = list[rs + rr];
          float w = topk_w[entry];
          o_buf[(size_t)entry * OUTD + col] = w * (acc[m][n][j] + b2v);
        }
      }
    }
  }
}

// ---------------- final: out = (o0 + o1) @ Wf + bf ----------------
__global__ __launch_bounds__(256) void final_kernel(
    const float* __restrict__ o_buf, const unsigned short* __restrict__ Wft,
    const float* __restrict__ bfv, float* __restrict__ out) {
  const int m0 = blockIdx.y * 128, n0 = blockIdx.x * 128;

  __shared__ unsigned short As[128 * 64];
  __shared__ unsigned short Bs[128 * 64];

  const int tid = threadIdx.x;
  const int wave = tid >> 6, lane = tid & 63;
  const int lrow = lane >> 3;
  const int lcol = (lane & 7) * 8;

  const unsigned short* bsrc[4];
#pragma unroll
  for (int i = 0; i < 4; i++) {
    int sr = (wave * 4 + i) * 8 + lrow;
    bsrc[i] = Wft + (size_t)(n0 + sr) * DIM + lcol;
  }

  const int wm = (wave >> 1) * 64, wn = (wave & 1) * 64;
  const int lr = lane & 15, lk = lane >> 4;

  f32x4 acc[4][4];
  const f32x4 zero = {0.f, 0.f, 0.f, 0.f};
#pragma unroll
  for (int m = 0; m < 4; m++)
#pragma unroll
    for (int n = 0; n < 4; n++) acc[m][n] = zero;

  for (int k0 = 0; k0 < DIM; k0 += 64) {
#pragma unroll
    for (int g = 0; g < 8; g++) {
      int idx = g * 256 + tid;
      int r = idx >> 4;
      int c4 = (idx & 15) * 4;
      const float4 v0 = *(const float4*)&o_buf[(size_t)(m0 + r) * 2 * OUTD + k0 + c4];
      const float4 v1 = *(const float4*)&o_buf[(size_t)(m0 + r) * 2 * OUTD + OUTD + k0 + c4];
      ushort4 u;
      u.x = f2bf(v0.x + v1.x); u.y = f2bf(v0.y + v1.y);
      u.z = f2bf(v0.z + v1.z); u.w = f2bf(v0.w + v1.w);
      *(ushort4*)&As[r * 64 + c4] = u;
    }
#pragma unroll
    for (int i = 0; i < 4; i++) gload16(bsrc[i] + k0, &Bs[(wave * 4 + i) * 512]);
    __syncthreads();
#pragma unroll
    for (int kk = 0; kk < 2; kk++) {
      bf16x8 a[4], b[4];
#pragma unroll
      for (int m = 0; m < 4; m++)
        a[m] = *(const bf16x8*)&As[(wm + m * 16 + lr) * 64 + kk * 32 + lk * 8];
#pragma unroll
      for (int n = 0; n < 4; n++)
        b[n] = *(const bf16x8*)&Bs[(wn + n * 16 + lr) * 64 + kk * 32 + lk * 8];
#pragma unroll
      for (int m = 0; m < 4; m++)
#pragma unroll
        for (int n = 0; n < 4; n++)
          acc[m][n] = __builtin_amdgcn_mfma_f32_16x16x32_bf16(a[m], b[n], acc[m][n], 0, 0, 0);
    }
    __syncthreads();
  }

#pragma unroll
  for (int n = 0; n < 4; n++) {
    int col = n0 + wn + n * 16 + lr;
    float bv = bfv[col];
#pragma unroll
    for (int m = 0; m < 4; m++) {
#pragma unroll
      for (int j = 0; j < 4; j++) {
        int r = m0 + wm + m * 16 + lk * 4 + j;
        out[(size_t)r * OUTD + col] = acc[m][n][j] + bv;
      }
    }
  }
}

extern "C" void kernel_launch(void* const* d_in, const int* in_sizes, int n_in,
                              void* d_out, int out_size, void* d_ws, size_t ws_size,
                              hipStream_t stream) {
  const float* X   = (const float*)d_in[0];
  const float* W1  = (const float*)d_in[1];
  const float* b1  = (const float*)d_in[2];
  const float* W3  = (const float*)d_in[3];
  const float* b3  = (const float*)d_in[4];
  const float* W2  = (const float*)d_in[5];
  const float* b2  = (const float*)d_in[6];
  const float* Wg  = (const float*)d_in[7];
  const float* bg  = (const float*)d_in[8];
  const float* Wf  = (const float*)d_in[9];
  const float* bfv = (const float*)d_in[10];
  float* out = (float*)d_out;

  char* p = (char*)d_ws;
  auto alloc = [&](size_t bytes) { char* r = p; p += (bytes + 255) & ~(size_t)255; return r; };
  unsigned short* Xb   = (unsigned short*)alloc((size_t)NTOK * DIM * 2);
  unsigned short* W13t = (unsigned short*)alloc((size_t)NE * 2 * HID * DIM * 2);
  unsigned short* W2t  = (unsigned short*)alloc((size_t)NE * OUTD * HID * 2);
  unsigned short* Wft  = (unsigned short*)alloc((size_t)OUTD * DIM * 2);
  unsigned short* hbuf = (unsigned short*)alloc((size_t)(NTOK * 2 + 256) * HID * 2);
  float* o_buf         = (float*)alloc((size_t)NTOK * 2 * OUTD * 4);
  int* topk_idx        = (int*)alloc(NTOK * 2 * 4);
  float* topk_w        = (float*)alloc(NTOK * 2 * 4);
  int* counts          = (int*)alloc(2 * NE * 4);
  int* cursors         = counts + NE;
  int* row_start       = (int*)alloc(NE * 4);
  int* list            = (int*)alloc(NTOK * 2 * 4);

  hipFuncSetAttribute((const void*)ffn_a_kernel,
                      hipFuncAttributeMaxDynamicSharedMemorySize, 131072);
  hipFuncSetAttribute((const void*)ffn_b_kernel,
                      hipFuncAttributeMaxDynamicSharedMemorySize, 98304);

  hipMemsetAsync(counts, 0, 2 * NE * sizeof(int), stream);

  cast_x_kernel<<<(NTOK * DIM / 8 + 255) / 256, 256, 0, stream>>>(X, Xb, NTOK * DIM / 8);
  tcast_i_kernel<<<dim3(HID / 32, DIM / 32, NE), 256, 0, stream>>>(W1, W13t, 0);
  tcast_i_kernel<<<dim3(HID / 32, DIM / 32, NE), 256, 0, stream>>>(W3, W13t, 1);
  tcast_kernel<<<dim3(OUTD / 32, HID / 32, NE), 256, 0, stream>>>(W2, W2t, HID, OUTD);
  tcast_kernel<<<dim3(OUTD / 32, DIM / 32, 1), 256, 0, stream>>>(Wf, Wft, DIM, OUTD);

  gating_kernel<<<NTOK, 64, 0, stream>>>(X, Wg, bg, topk_idx, topk_w, counts);
  finalize_kernel<<<1, 64, 0, stream>>>(counts, row_start);
  scatter_kernel<<<NTOK / 256, 256, 0, stream>>>(topk_idx, row_start, cursors, list);

  ffn_a_kernel<<<dim3(2 * HID / 256, 16, NE), 512, 131072, stream>>>(
      Xb, W13t, b1, b3, counts, row_start, list, hbuf);
  ffn_b_kernel<<<dim3(OUTD / 256, 32, NE), 512, 98304, stream>>>(
      hbuf, W2t, b2, counts, row_start, list, topk_w, o_buf);
  final_kernel<<<dim3(OUTD / 128, NTOK / 128), 256, 0, stream>>>(o_buf, Wft, bfv, out);
}

// Round 4
// 483.299 us; speedup vs baseline: 1.2705x; 1.0183x over previous
//
#include <hip/hip_runtime.h>

#define DIM  1024
#define HID  2048
#define OUTD 1024
#define NE   8
#define NTOK 4096

using bf16x8 = __attribute__((ext_vector_type(8))) short;
using f32x4  = __attribute__((ext_vector_type(4))) float;

__device__ __forceinline__ unsigned short f2bf(float f) {
  unsigned int u = __builtin_bit_cast(unsigned int, f);
  u += 0x7fff + ((u >> 16) & 1);   // round-to-nearest-even
  return (unsigned short)(u >> 16);
}

__device__ __forceinline__ void gload16(const void* g, void* l) {
  __builtin_amdgcn_global_load_lds(
      (const __attribute__((address_space(1))) void*)g,
      (__attribute__((address_space(3))) void*)l, 16, 0, 0);
}

#define BARR __builtin_amdgcn_s_barrier()
#define VMC(n) asm volatile("s_waitcnt vmcnt(" #n ")" ::: "memory")

// ---------------- cast X fp32 -> bf16 ----------------
__global__ void cast_x_kernel(const float* __restrict__ in,
                              unsigned short* __restrict__ out, int n8) {
  int i = blockIdx.x * blockDim.x + threadIdx.x;
  if (i >= n8) return;
  const float4* p = (const float4*)(in + (size_t)i * 8);
  float4 a = p[0], b = p[1];
  ushort4 u0, u1;
  u0.x = f2bf(a.x); u0.y = f2bf(a.y); u0.z = f2bf(a.z); u0.w = f2bf(a.w);
  u1.x = f2bf(b.x); u1.y = f2bf(b.y); u1.z = f2bf(b.z); u1.w = f2bf(b.w);
  *(ushort4*)(out + (size_t)i * 8)     = u0;
  *(ushort4*)(out + (size_t)i * 8 + 4) = u1;
}

// ---------------- transpose + cast: in [R][C] fp32 -> out [C][R] bf16 ----------------
__global__ void tcast_kernel(const float* __restrict__ in,
                             unsigned short* __restrict__ out, int R, int C) {
  __shared__ float tile[32][33];
  size_t zo = (size_t)blockIdx.z * R * C;
  int c0 = blockIdx.x * 32, r0 = blockIdx.y * 32;
  int tx = threadIdx.x & 31, ty = threadIdx.x >> 5;
#pragma unroll
  for (int j = 0; j < 4; j++) {
    int r = ty + j * 8;
    tile[r][tx] = in[zo + (size_t)(r0 + r) * C + c0 + tx];
  }
  __syncthreads();
#pragma unroll
  for (int j = 0; j < 4; j++) {
    int c = ty + j * 8;
    out[zo + (size_t)(c0 + c) * R + r0 + tx] = f2bf(tile[tx][c]);
  }
}

// ---- transpose+cast W1/W3 [NE][DIM][HID] into interleaved W13t [NE][2*HID][DIM]
__global__ void tcast_i_kernel(const float* __restrict__ in,
                               unsigned short* __restrict__ out, int s) {
  __shared__ float tile[32][33];
  int e = blockIdx.z;
  const float* inp = in + (size_t)e * DIM * HID;
  unsigned short* op = out + (size_t)e * 2 * HID * DIM;
  int c0 = blockIdx.x * 32, r0 = blockIdx.y * 32;
  int tx = threadIdx.x & 31, ty = threadIdx.x >> 5;
#pragma unroll
  for (int j = 0; j < 4; j++) {
    int r = ty + j * 8;
    tile[r][tx] = inp[(size_t)(r0 + r) * HID + c0 + tx];
  }
  __syncthreads();
#pragma unroll
  for (int j = 0; j < 4; j++) {
    int c = ty + j * 8;
    int h = c0 + c;
    int orow = 32 * (h >> 4) + 16 * s + (h & 15);
    op[(size_t)orow * DIM + r0 + tx] = f2bf(tile[tx][c]);
  }
}

// ---------------- gating ----------------
__global__ void gating_kernel(const float* __restrict__ X, const float* __restrict__ Wg,
                              const float* __restrict__ bg, int* __restrict__ topk_idx,
                              float* __restrict__ topk_w, int* __restrict__ counts) {
  int t = blockIdx.x, lane = threadIdx.x;
  float acc[NE];
#pragma unroll
  for (int e = 0; e < NE; e++) acc[e] = 0.f;
  for (int d = lane; d < DIM; d += 64) {
    float xv = X[(size_t)t * DIM + d];
#pragma unroll
    for (int e = 0; e < NE; e++) acc[e] += xv * Wg[d * NE + e];
  }
#pragma unroll
  for (int e = 0; e < NE; e++) {
#pragma unroll
    for (int off = 32; off > 0; off >>= 1) acc[e] += __shfl_xor(acc[e], off, 64);
  }
  if (lane == 0) {
    float p[NE];
    float mx = -1e30f;
#pragma unroll
    for (int e = 0; e < NE; e++) { p[e] = acc[e] + bg[e]; mx = fmaxf(mx, p[e]); }
    float s = 0.f;
#pragma unroll
    for (int e = 0; e < NE; e++) { p[e] = expf(p[e] - mx); s += p[e]; }
    float inv = 1.f / s;
#pragma unroll
    for (int e = 0; e < NE; e++) p[e] *= inv;
    int i1 = 0; float v1 = p[0];
#pragma unroll
    for (int e = 1; e < NE; e++) if (p[e] >= v1) { v1 = p[e]; i1 = e; }
    int i2 = (i1 == 0) ? 1 : 0; float v2 = p[i2];
#pragma unroll
    for (int e = 0; e < NE; e++) {
      if (e == i1) continue;
      if (p[e] >= v2 && e != i2) { v2 = p[e]; i2 = e; }
    }
    topk_idx[t * 2 + 0] = i1; topk_idx[t * 2 + 1] = i2;
    topk_w[t * 2 + 0] = v1;  topk_w[t * 2 + 1] = v2;
    atomicAdd(&counts[i1], 1); atomicAdd(&counts[i2], 1);
  }
}

// row_start prefix + tile prefix (BM=256 for both GEMMs)
__global__ void finalize_kernel(const int* __restrict__ counts, int* __restrict__ row_start,
                                int* __restrict__ tp) {
  if (threadIdx.x == 0) {
    int s = 0, t = 0;
#pragma unroll
    for (int e = 0; e < NE; e++) {
      row_start[e] = s; tp[e] = t;
      s += counts[e]; t += (counts[e] + 255) >> 8;
    }
    tp[NE] = t;
  }
}

__global__ void scatter_kernel(const int* __restrict__ topk_idx, const int* __restrict__ row_start,
                               int* __restrict__ cursors, int* __restrict__ list) {
  int t = blockIdx.x * blockDim.x + threadIdx.x;
  if (t >= NTOK) return;
#pragma unroll
  for (int s = 0; s < 2; s++) {
    int e = topk_idx[t * 2 + s];
    int pos = atomicAdd(&cursors[e], 1);
    list[row_start[e] + pos] = (t << 1) | s;
  }
}

// ================= stage A: 256x256, BK=64, 8-phase counted-vmcnt =================
// LDS per dbuf (one K-tile): Ak0[256][32] Ak1[256][32] Bk0[256][32] Bk1[256][32]
// dbuf stride 32768 shorts; even K-tiles -> dbuf0, odd -> dbuf1.
#define FA_NT 16
#define FA_IT 8
__global__ __launch_bounds__(512, 2) void ffn_a_kernel(
    const unsigned short* __restrict__ Xb,
    const unsigned short* __restrict__ W13t,
    const float* __restrict__ b1, const float* __restrict__ b3,
    const int* __restrict__ counts, const int* __restrict__ row_start,
    const int* __restrict__ tp,
    const int* __restrict__ list, unsigned short* __restrict__ h_buf) {
  extern __shared__ unsigned short lds[];
  const int by = blockIdx.y;
  int e = 0;
#pragma unroll
  for (int k = 0; k < NE; k++) if (by >= tp[k + 1]) e = k + 1;
  if (e >= NE || by >= tp[NE]) return;
  const int ne = counts[e];
  const int rs = row_start[e];
  const int m0 = (by - tp[e]) * 256;
  const int n0 = blockIdx.x * 256;

  const int tid = threadIdx.x;
  const int wave = tid >> 6, lane = tid & 63;
  const int lr = lane & 15, lk = lane >> 4;
  const int WM = (wave >> 2) * 128, WN = (wave & 3) * 64;

  // staging sources: row r = c*128 + wave*16 + (lane>>2), 16B slot = lane&3
  const int scol = (lane & 3) * 8;
  const unsigned short* aptr[2];
  const unsigned short* bptr[2];
#pragma unroll
  for (int c = 0; c < 2; c++) {
    int r = c * 128 + wave * 16 + (lane >> 2);
    int rr = m0 + r; if (rr >= ne) rr = m0;
    int tok = list[rs + rr] >> 1;
    aptr[c] = Xb + (size_t)tok * DIM + scol;
    bptr[c] = W13t + ((size_t)e * 2 * HID + n0 + r) * DIM + scol;
  }

  f32x4 acc[8][4];
  const f32x4 zero = {0.f, 0.f, 0.f, 0.f};
#pragma unroll
  for (int m = 0; m < 8; m++)
#pragma unroll
    for (int n = 0; n < 4; n++) acc[m][n] = zero;

  bf16x8 aa[4], bb[4];

  auto STG = [&](int tile, int isB, int kk) {      // stage one half-tile (2 loads)
    if (tile >= FA_NT) return;
    unsigned short* hb = lds + (tile & 1) * 32768 + isB * 16384 + kk * 8192 + wave * 512;
    const int ko = tile * 64 + kk * 32;
    if (!isB) { gload16(aptr[0] + ko, hb); gload16(aptr[1] + ko, hb + 4096); }
    else      { gload16(bptr[0] + ko, hb); gload16(bptr[1] + ko, hb + 4096); }
  };
  auto DSB = [&](int d, int kk) {
#pragma unroll
    for (int n = 0; n < 4; n++) {
      int row = WN + n * 16 + lr;
      bb[n] = *(const bf16x8*)&lds[d * 32768 + 16384 + kk * 8192 + row * 32 + lk * 8];
    }
  };
  auto DSA = [&](int d, int kk, int mh) {
#pragma unroll
    for (int mi = 0; mi < 4; mi++) {
      int row = WM + (mh * 4 + mi) * 16 + lr;
      aa[mi] = *(const bf16x8*)&lds[d * 32768 + kk * 8192 + row * 32 + lk * 8];
    }
  };
  auto MM = [&](int mh) {
    __builtin_amdgcn_s_setprio(1);
#pragma unroll
    for (int mi = 0; mi < 4; mi++)
#pragma unroll
      for (int n = 0; n < 4; n++)
        acc[mh * 4 + mi][n] =
            __builtin_amdgcn_mfma_f32_16x16x32_bf16(aa[mi], bb[n], acc[mh * 4 + mi][n], 0, 0, 0);
    __builtin_amdgcn_s_setprio(0);
  };

  // prologue: t0 fully + 3 halves of t1; vmcnt(6) -> t0's 8 loads landed
  STG(0, 0, 0); STG(0, 1, 0); STG(0, 0, 1); STG(0, 1, 1);
  STG(1, 1, 0); STG(1, 0, 0); STG(1, 1, 1);
  VMC(6); BARR;

  for (int i = 0; i < FA_IT; ++i) {
    const int t1 = 2 * i + 1, t2 = 2 * i + 2, t3 = 2 * i + 3;
    // P1: quad(m0,k0) of t0 | stage Ak1(t1)
    DSB(0, 0); DSA(0, 0, 0); STG(t1, 0, 1); BARR; MM(0); BARR;
    // P2: quad(m1,k0)       | stage Bk0(t2)  [Bk0(t0) consumed in P1]
    DSA(0, 0, 1); STG(t2, 1, 0); BARR; MM(1); BARR;
    // P3: quad(m0,k1)       | stage Ak0(t2)  [Ak0(t0) consumed in P2]
    DSB(0, 1); DSA(0, 1, 0); STG(t2, 0, 0); BARR; MM(0); BARR;
    // P4: quad(m1,k1)       | stage Bk1(t2)  [Bk1(t0) consumed in P3]
    // vmcnt(6): outstanding = P2,P3,P4 (6) -> P1's Ak1(t1) landed -> t1 complete
    DSA(0, 1, 1); STG(t2, 1, 1);
    if (i < FA_IT - 1) { VMC(6); } else { VMC(0); }
    BARR; MM(1); BARR;
    // P5: t1 quad(m0,k0)    | stage Ak1(t2)  [Ak1(t0) consumed in P4]
    DSB(1, 0); DSA(1, 0, 0); STG(t2, 0, 1); BARR; MM(0); BARR;
    // P6                    | stage Bk0(t3)
    DSA(1, 0, 1); STG(t3, 1, 0); BARR; MM(1); BARR;
    // P7                    | stage Ak0(t3)
    DSB(1, 1); DSA(1, 1, 0); STG(t3, 0, 0); BARR; MM(0); BARR;
    // P8                    | stage Bk1(t3); vmcnt(6) -> P5's Ak1(t2) landed -> t2 complete
    DSA(1, 1, 1); STG(t3, 1, 1);
    if (i < FA_IT - 1) { VMC(6); }
    BARR; MM(1); BARR;
  }

  // SwiGLU epilogue
  const int hbase = (n0 + WN) >> 1;
#pragma unroll
  for (int g = 0; g < 2; g++) {
    int h = hbase + g * 16 + lr;
    float b1v = b1[e * HID + h];
    float b3v = b3[e * HID + h];
#pragma unroll
    for (int m = 0; m < 8; m++) {
#pragma unroll
      for (int j = 0; j < 4; j++) {
        int rr = m0 + WM + m * 16 + lk * 4 + j;
        if (rr < ne) {
          float h1 = acc[m][2 * g][j] + b1v;
          float h3 = acc[m][2 * g + 1][j] + b3v;
          float v = h1 * h3;
          h_buf[(size_t)(rs + rr) * HID + h] = f2bf(v / (1.f + expf(-v)));
        }
      }
    }
  }
}

// ================= stage B: 256x128, BK=64, 8-phase counted-vmcnt =================
// LDS per dbuf: Ak0[256][32] Ak1[256][32] Bk0[128][32] Bk1[128][32] = 24576 shorts
#define FB_NT 32
#define FB_IT 16
__global__ __launch_bounds__(512, 2) void ffn_b_kernel(
    const unsigned short* __restrict__ h_buf,
    const unsigned short* __restrict__ W2t,
    const float* __restrict__ b2,
    const int* __restrict__ counts, const int* __restrict__ row_start,
    const int* __restrict__ tp,
    const int* __restrict__ list, const float* __restrict__ topk_w,
    float* __restrict__ o_buf) {
  extern __shared__ unsigned short lds[];
  const int by = blockIdx.y;
  int e = 0;
#pragma unroll
  for (int k = 0; k < NE; k++) if (by >= tp[k + 1]) e = k + 1;
  if (e >= NE || by >= tp[NE]) return;
  const int ne = counts[e];
  const int rs = row_start[e];
  const int m0 = (by - tp[e]) * 256;
  const int n0 = blockIdx.x * 128;

  const int tid = threadIdx.x;
  const int wave = tid >> 6, lane = tid & 63;
  const int lr = lane & 15, lk = lane >> 4;
  const int WM = (wave >> 2) * 128, WN = (wave & 3) * 32;

  const int scol = (lane & 3) * 8;
  const unsigned short* aptr[2];
  const unsigned short* bptr;
#pragma unroll
  for (int c = 0; c < 2; c++) {
    int r = c * 128 + wave * 16 + (lane >> 2);
    aptr[c] = h_buf + (size_t)(rs + m0 + r) * HID + scol;   // padded rows, in-bounds
  }
  {
    int r = wave * 16 + (lane >> 2);                        // 0..127
    bptr = W2t + ((size_t)e * OUTD + n0 + r) * HID + scol;
  }

  f32x4 acc[8][2];
  const f32x4 zero = {0.f, 0.f, 0.f, 0.f};
#pragma unroll
  for (int m = 0; m < 8; m++)
#pragma unroll
    for (int n = 0; n < 2; n++) acc[m][n] = zero;

  bf16x8 aa[4], bb[2];

  auto STG = [&](int tile, int isB, int kk) {   // A half = 2 loads, B half = 1 load
    if (tile >= FB_NT) return;
    const int ko = tile * 64 + kk * 32;
    if (!isB) {
      unsigned short* hb = lds + (tile & 1) * 24576 + kk * 8192 + wave * 512;
      gload16(aptr[0] + ko, hb); gload16(aptr[1] + ko, hb + 4096);
    } else {
      unsigned short* hb = lds + (tile & 1) * 24576 + 16384 + kk * 4096 + wave * 512;
      gload16(bptr + ko, hb);
    }
  };
  auto DSB = [&](int d, int kk) {
#pragma unroll
    for (int n = 0; n < 2; n++) {
      int row = WN + n * 16 + lr;
      bb[n] = *(const bf16x8*)&lds[d * 24576 + 16384 + kk * 4096 + row * 32 + lk * 8];
    }
  };
  auto DSA = [&](int d, int kk, int mh) {
#pragma unroll
    for (int mi = 0; mi < 4; mi++) {
      int row = WM + (mh * 4 + mi) * 16 + lr;
      aa[mi] = *(const bf16x8*)&lds[d * 24576 + kk * 8192 + row * 32 + lk * 8];
    }
  };
  auto MM = [&](int mh) {
    __builtin_amdgcn_s_setprio(1);
#pragma unroll
    for (int mi = 0; mi < 4; mi++)
#pragma unroll
      for (int n = 0; n < 2; n++)
        acc[mh * 4 + mi][n] =
            __builtin_amdgcn_mfma_f32_16x16x32_bf16(aa[mi], bb[n], acc[mh * 4 + mi][n], 0, 0, 0);
    __builtin_amdgcn_s_setprio(0);
  };

  // prologue: t0 (6 loads) + {Bk0,Ak0,Bk1}(t1) (4 loads); vmcnt(4) -> t0 landed
  STG(0, 0, 0); STG(0, 1, 0); STG(0, 0, 1); STG(0, 1, 1);
  STG(1, 1, 0); STG(1, 0, 0); STG(1, 1, 1);
  VMC(4); BARR;

  for (int i = 0; i < FB_IT; ++i) {
    const int t1 = 2 * i + 1, t2 = 2 * i + 2, t3 = 2 * i + 3;
    DSB(0, 0); DSA(0, 0, 0); STG(t1, 0, 1); BARR; MM(0); BARR;
    DSA(0, 0, 1); STG(t2, 1, 0); BARR; MM(1); BARR;
    DSB(0, 1); DSA(0, 1, 0); STG(t2, 0, 0); BARR; MM(0); BARR;
    // vmcnt(4): outstanding = P2(1)+P3(2)+P4(1) -> P1's Ak1(t1) landed
    DSA(0, 1, 1); STG(t2, 1, 1);
    if (i < FB_IT - 1) { VMC(4); } else { VMC(0); }
    BARR; MM(1); BARR;
    DSB(1, 0); DSA(1, 0, 0); STG(t2, 0, 1); BARR; MM(0); BARR;
    DSA(1, 0, 1); STG(t3, 1, 0); BARR; MM(1); BARR;
    DSB(1, 1); DSA(1, 1, 0); STG(t3, 0, 0); BARR; MM(0); BARR;
    DSA(1, 1, 1); STG(t3, 1, 1);
    if (i < FB_IT - 1) { VMC(4); }
    BARR; MM(1); BARR;
  }

#pragma unroll
  for (int n = 0; n < 2; n++) {
    int col = n0 + WN + n * 16 + lr;
    float b2v = b2[e * OUTD + col];
#pragma unroll
    for (int m = 0; m < 8; m++) {
#pragma unroll
      for (int j = 0; j < 4; j++) {
        int rr = m0 + WM + m * 16 + lk * 4 + j;
        if (rr < ne) {
          int entry = list[rs + rr];
          float w = topk_w[entry];
          o_buf[(size_t)entry * OUTD + col] = w * (acc[m][n][j] + b2v);
        }
      }
    }
  }
}

// ---------------- final: out = (o0 + o1) @ Wf + bf ----------------
__global__ __launch_bounds__(256) void final_kernel(
    const float* __restrict__ o_buf, const unsigned short* __restrict__ Wft,
    const float* __restrict__ bfv, float* __restrict__ out) {
  const int m0 = blockIdx.y * 128, n0 = blockIdx.x * 128;

  __shared__ unsigned short As[128 * 64];
  __shared__ unsigned short Bs[128 * 64];

  const int tid = threadIdx.x;
  const int wave = tid >> 6, lane = tid & 63;
  const int lrow = lane >> 3;
  const int lcol = (lane & 7) * 8;

  const unsigned short* bsrc[4];
#pragma unroll
  for (int i = 0; i < 4; i++) {
    int sr = (wave * 4 + i) * 8 + lrow;
    bsrc[i] = Wft + (size_t)(n0 + sr) * DIM + lcol;
  }

  const int wm = (wave >> 1) * 64, wn = (wave & 1) * 64;
  const int lr = lane & 15, lk = lane >> 4;

  f32x4 acc[4][4];
  const f32x4 zero = {0.f, 0.f, 0.f, 0.f};
#pragma unroll
  for (int m = 0; m < 4; m++)
#pragma unroll
    for (int n = 0; n < 4; n++) acc[m][n] = zero;

  for (int k0 = 0; k0 < DIM; k0 += 64) {
#pragma unroll
    for (int g = 0; g < 8; g++) {
      int idx = g * 256 + tid;
      int r = idx >> 4;
      int c4 = (idx & 15) * 4;
      const float4 v0 = *(const float4*)&o_buf[(size_t)(m0 + r) * 2 * OUTD + k0 + c4];
      const float4 v1 = *(const float4*)&o_buf[(size_t)(m0 + r) * 2 * OUTD + OUTD + k0 + c4];
      ushort4 u;
      u.x = f2bf(v0.x + v1.x); u.y = f2bf(v0.y + v1.y);
      u.z = f2bf(v0.z + v1.z); u.w = f2bf(v0.w + v1.w);
      *(ushort4*)&As[r * 64 + c4] = u;
    }
#pragma unroll
    for (int i = 0; i < 4; i++) gload16(bsrc[i] + k0, &Bs[(wave * 4 + i) * 512]);
    __syncthreads();
#pragma unroll
    for (int kk = 0; kk < 2; kk++) {
      bf16x8 a[4], b[4];
#pragma unroll
      for (int m = 0; m < 4; m++)
        a[m] = *(const bf16x8*)&As[(wm + m * 16 + lr) * 64 + kk * 32 + lk * 8];
#pragma unroll
      for (int n = 0; n < 4; n++)
        b[n] = *(const bf16x8*)&Bs[(wn + n * 16 + lr) * 64 + kk * 32 + lk * 8];
#pragma unroll
      for (int m = 0; m < 4; m++)
#pragma unroll
        for (int n = 0; n < 4; n++)
          acc[m][n] = __builtin_amdgcn_mfma_f32_16x16x32_bf16(a[m], b[n], acc[m][n], 0, 0, 0);
    }
    __syncthreads();
  }

#pragma unroll
  for (int n = 0; n < 4; n++) {
    int col = n0 + wn + n * 16 + lr;
    float bv = bfv[col];
#pragma unroll
    for (int m = 0; m < 4; m++) {
#pragma unroll
      for (int j = 0; j < 4; j++) {
        int r = m0 + wm + m * 16 + lk * 4 + j;
        out[(size_t)r * OUTD + col] = acc[m][n][j] + bv;
      }
    }
  }
}

extern "C" void kernel_launch(void* const* d_in, const int* in_sizes, int n_in,
                              void* d_out, int out_size, void* d_ws, size_t ws_size,
                              hipStream_t stream) {
  const float* X   = (const float*)d_in[0];
  const float* W1  = (const float*)d_in[1];
  const float* b1  = (const float*)d_in[2];
  const float* W3  = (const float*)d_in[3];
  const float* b3  = (const float*)d_in[4];
  const float* W2  = (const float*)d_in[5];
  const float* b2  = (const float*)d_in[6];
  const float* Wg  = (const float*)d_in[7];
  const float* bg  = (const float*)d_in[8];
  const float* Wf  = (const float*)d_in[9];
  const float* bfv = (const float*)d_in[10];
  float* out = (float*)d_out;

  char* p = (char*)d_ws;
  auto alloc = [&](size_t bytes) { char* r = p; p += (bytes + 255) & ~(size_t)255; return r; };
  unsigned short* Xb   = (unsigned short*)alloc((size_t)NTOK * DIM * 2);
  unsigned short* W13t = (unsigned short*)alloc((size_t)NE * 2 * HID * DIM * 2);
  unsigned short* W2t  = (unsigned short*)alloc((size_t)NE * OUTD * HID * 2);
  unsigned short* Wft  = (unsigned short*)alloc((size_t)OUTD * DIM * 2);
  unsigned short* hbuf = (unsigned short*)alloc((size_t)(NTOK * 2 + 256) * HID * 2);
  float* o_buf         = (float*)alloc((size_t)NTOK * 2 * OUTD * 4);
  int* topk_idx        = (int*)alloc(NTOK * 2 * 4);
  float* topk_w        = (float*)alloc(NTOK * 2 * 4);
  int* counts          = (int*)alloc(2 * NE * 4);
  int* cursors         = counts + NE;
  int* row_start       = (int*)alloc(NE * 4);
  int* tp              = (int*)alloc((NE + 1) * 4);
  int* list            = (int*)alloc(NTOK * 2 * 4);

  hipFuncSetAttribute((const void*)ffn_a_kernel,
                      hipFuncAttributeMaxDynamicSharedMemorySize, 131072);
  hipFuncSetAttribute((const void*)ffn_b_kernel,
                      hipFuncAttributeMaxDynamicSharedMemorySize, 98304);

  hipMemsetAsync(counts, 0, 2 * NE * sizeof(int), stream);

  cast_x_kernel<<<(NTOK * DIM / 8 + 255) / 256, 256, 0, stream>>>(X, Xb, NTOK * DIM / 8);
  tcast_i_kernel<<<dim3(HID / 32, DIM / 32, NE), 256, 0, stream>>>(W1, W13t, 0);
  tcast_i_kernel<<<dim3(HID / 32, DIM / 32, NE), 256, 0, stream>>>(W3, W13t, 1);
  tcast_kernel<<<dim3(OUTD / 32, HID / 32, NE), 256, 0, stream>>>(W2, W2t, HID, OUTD);
  tcast_kernel<<<dim3(OUTD / 32, DIM / 32, 1), 256, 0, stream>>>(Wf, Wft, DIM, OUTD);

  gating_kernel<<<NTOK, 64, 0, stream>>>(X, Wg, bg, topk_idx, topk_w, counts);
  finalize_kernel<<<1, 64, 0, stream>>>(counts, row_start, tp);
  scatter_kernel<<<NTOK / 256, 256, 0, stream>>>(topk_idx, row_start, cursors, list);

  // tile-compact grids: y = tile index (max sum ceil(ne/256) = 39 -> 40)
  ffn_a_kernel<<<dim3(2 * HID / 256, 40), 512, 131072, stream>>>(
      Xb, W13t, b1, b3, counts, row_start, tp, list, hbuf);
  ffn_b_kernel<<<dim3(OUTD / 128, 40), 512, 98304, stream>>>(
      hbuf, W2t, b2, counts, row_start, tp, list, topk_w, o_buf);
  final_kernel<<<dim3(OUTD / 128, NTOK / 128), 256, 0, stream>>>(o_buf, Wft, bfv, out);
}

// Round 5
// 443.900 us; speedup vs baseline: 1.3832x; 1.0888x over previous
//
#include <hip/hip_runtime.h>

#define DIM  1024
#define HID  2048
#define OUTD 1024
#define NE   8
#define NTOK 4096

using bf16x8 = __attribute__((ext_vector_type(8))) short;
using f32x4  = __attribute__((ext_vector_type(4))) float;

__device__ __forceinline__ unsigned short f2bf(float f) {
  unsigned int u = __builtin_bit_cast(unsigned int, f);
  u += 0x7fff + ((u >> 16) & 1);   // round-to-nearest-even
  return (unsigned short)(u >> 16);
}

__device__ __forceinline__ void gload16(const void* g, void* l) {
  __builtin_amdgcn_global_load_lds(
      (const __attribute__((address_space(1))) void*)g,
      (__attribute__((address_space(3))) void*)l, 16, 0, 0);
}

// ---------------- cast X fp32 -> bf16 ----------------
__global__ void cast_x_kernel(const float* __restrict__ in,
                              unsigned short* __restrict__ out, int n8) {
  int i = blockIdx.x * blockDim.x + threadIdx.x;
  if (i >= n8) return;
  const float4* p = (const float4*)(in + (size_t)i * 8);
  float4 a = p[0], b = p[1];
  ushort4 u0, u1;
  u0.x = f2bf(a.x); u0.y = f2bf(a.y); u0.z = f2bf(a.z); u0.w = f2bf(a.w);
  u1.x = f2bf(b.x); u1.y = f2bf(b.y); u1.z = f2bf(b.z); u1.w = f2bf(b.w);
  *(ushort4*)(out + (size_t)i * 8)     = u0;
  *(ushort4*)(out + (size_t)i * 8 + 4) = u1;
}

// ---------------- transpose + cast: in [R][C] fp32 -> out [C][R] bf16 ----------------
__global__ void tcast_kernel(const float* __restrict__ in,
                             unsigned short* __restrict__ out, int R, int C) {
  __shared__ float tile[32][33];
  size_t zo = (size_t)blockIdx.z * R * C;
  int c0 = blockIdx.x * 32, r0 = blockIdx.y * 32;
  int tx = threadIdx.x & 31, ty = threadIdx.x >> 5;
#pragma unroll
  for (int j = 0; j < 4; j++) {
    int r = ty + j * 8;
    tile[r][tx] = in[zo + (size_t)(r0 + r) * C + c0 + tx];
  }
  __syncthreads();
#pragma unroll
  for (int j = 0; j < 4; j++) {
    int c = ty + j * 8;
    out[zo + (size_t)(c0 + c) * R + r0 + tx] = f2bf(tile[tx][c]);
  }
}

// ---- transpose+cast W1/W3 [NE][DIM][HID] into interleaved W13t [NE][2*HID][DIM]
__global__ void tcast_i_kernel(const float* __restrict__ in,
                               unsigned short* __restrict__ out, int s) {
  __shared__ float tile[32][33];
  int e = blockIdx.z;
  const float* inp = in + (size_t)e * DIM * HID;
  unsigned short* op = out + (size_t)e * 2 * HID * DIM;
  int c0 = blockIdx.x * 32, r0 = blockIdx.y * 32;
  int tx = threadIdx.x & 31, ty = threadIdx.x >> 5;
#pragma unroll
  for (int j = 0; j < 4; j++) {
    int r = ty + j * 8;
    tile[r][tx] = inp[(size_t)(r0 + r) * HID + c0 + tx];
  }
  __syncthreads();
#pragma unroll
  for (int j = 0; j < 4; j++) {
    int c = ty + j * 8;
    int h = c0 + c;
    int orow = 32 * (h >> 4) + 16 * s + (h & 15);
    op[(size_t)orow * DIM + r0 + tx] = f2bf(tile[tx][c]);
  }
}

// ---------------- gating ----------------
__global__ void gating_kernel(const float* __restrict__ X, const float* __restrict__ Wg,
                              const float* __restrict__ bg, int* __restrict__ topk_idx,
                              float* __restrict__ topk_w, int* __restrict__ counts) {
  int t = blockIdx.x, lane = threadIdx.x;
  float acc[NE];
#pragma unroll
  for (int e = 0; e < NE; e++) acc[e] = 0.f;
  for (int d = lane; d < DIM; d += 64) {
    float xv = X[(size_t)t * DIM + d];
#pragma unroll
    for (int e = 0; e < NE; e++) acc[e] += xv * Wg[d * NE + e];
  }
#pragma unroll
  for (int e = 0; e < NE; e++) {
#pragma unroll
    for (int off = 32; off > 0; off >>= 1) acc[e] += __shfl_xor(acc[e], off, 64);
  }
  if (lane == 0) {
    float p[NE];
    float mx = -1e30f;
#pragma unroll
    for (int e = 0; e < NE; e++) { p[e] = acc[e] + bg[e]; mx = fmaxf(mx, p[e]); }
    float s = 0.f;
#pragma unroll
    for (int e = 0; e < NE; e++) { p[e] = expf(p[e] - mx); s += p[e]; }
    float inv = 1.f / s;
#pragma unroll
    for (int e = 0; e < NE; e++) p[e] *= inv;
    int i1 = 0; float v1 = p[0];
#pragma unroll
    for (int e = 1; e < NE; e++) if (p[e] >= v1) { v1 = p[e]; i1 = e; }
    int i2 = (i1 == 0) ? 1 : 0; float v2 = p[i2];
#pragma unroll
    for (int e = 0; e < NE; e++) {
      if (e == i1) continue;
      if (p[e] >= v2 && e != i2) { v2 = p[e]; i2 = e; }
    }
    topk_idx[t * 2 + 0] = i1; topk_idx[t * 2 + 1] = i2;
    topk_w[t * 2 + 0] = v1;  topk_w[t * 2 + 1] = v2;
    atomicAdd(&counts[i1], 1); atomicAdd(&counts[i2], 1);
  }
}

// row_start prefix + tile prefix (BM=128 for both GEMMs)
__global__ void finalize_kernel(const int* __restrict__ counts, int* __restrict__ row_start,
                                int* __restrict__ tp) {
  if (threadIdx.x == 0) {
    int s = 0, t = 0;
#pragma unroll
    for (int e = 0; e < NE; e++) {
      row_start[e] = s; tp[e] = t;
      s += counts[e]; t += (counts[e] + 127) >> 7;
    }
    tp[NE] = t;
  }
}

__global__ void scatter_kernel(const int* __restrict__ topk_idx, const int* __restrict__ row_start,
                               int* __restrict__ cursors, int* __restrict__ list) {
  int t = blockIdx.x * blockDim.x + threadIdx.x;
  if (t >= NTOK) return;
#pragma unroll
  for (int s = 0; s < 2; s++) {
    int e = topk_idx[t * 2 + s];
    int pos = atomicAdd(&cursors[e], 1);
    list[row_start[e] + pos] = (t << 1) | s;
  }
}

// ============ stage A: 128x128, BK=64, m97 single-buffer 2-barrier, swizzled ============
__global__ __launch_bounds__(256, 3) void ffn_a_kernel(
    const unsigned short* __restrict__ Xb,
    const unsigned short* __restrict__ W13t,
    const float* __restrict__ b1, const float* __restrict__ b3,
    const int* __restrict__ counts, const int* __restrict__ row_start,
    const int* __restrict__ tp, const int* __restrict__ list,
    unsigned short* __restrict__ h_buf) {
  __shared__ unsigned short As[128 * 64];
  __shared__ unsigned short Bs[128 * 64];
  const int by = blockIdx.y;
  if (by >= tp[NE]) return;
  int e = 0;
#pragma unroll
  for (int k = 1; k < NE; k++) if (by >= tp[k]) e = k;
  const int ne = counts[e], rs = row_start[e];
  const int m0 = (by - tp[e]) * 128;
  const int n0 = blockIdx.x * 128;           // interleaved col space [0,4096)

  const int tid = threadIdx.x;
  const int wave = tid >> 6, lane = tid & 63;
  const int lr = lane & 15, lk = lane >> 4;
  const int wm = (wave >> 1) * 64, wn = (wave & 1) * 64;

  // staging: instr (wave,i) covers rows (wave*4+i)*8 + (lane>>3), slot lane&7.
  // LDS slot s of row r holds global col16 (s ^ (r&7)); here r&7 == lane>>3.
  const int scs = ((lane & 7) ^ (lane >> 3)) * 8;   // swizzled source col (shorts)
  const unsigned short* asrc[4];
  const unsigned short* bsrc[4];
#pragma unroll
  for (int i = 0; i < 4; i++) {
    int sr = (wave * 4 + i) * 8 + (lane >> 3);
    int rr = m0 + sr; if (rr >= ne) rr = m0;
    int tok = list[rs + rr] >> 1;
    asrc[i] = Xb + (size_t)tok * DIM + scs;
    bsrc[i] = W13t + ((size_t)e * 2 * HID + n0 + sr) * DIM + scs;
  }

  f32x4 acc[4][4];
  const f32x4 zero = {0.f, 0.f, 0.f, 0.f};
#pragma unroll
  for (int m = 0; m < 4; m++)
#pragma unroll
    for (int n = 0; n < 4; n++) acc[m][n] = zero;

  const int sx = lr & 7;    // row&7 for all frag rows this lane reads

  for (int k0 = 0; k0 < DIM; k0 += 64) {
#pragma unroll
    for (int i = 0; i < 4; i++) {
      gload16(asrc[i] + k0, &As[(wave * 4 + i) * 512]);
      gload16(bsrc[i] + k0, &Bs[(wave * 4 + i) * 512]);
    }
    __syncthreads();
#pragma unroll
    for (int kk = 0; kk < 2; kk++) {
      const int sl = ((kk * 4 + lk) ^ sx) * 8;
      bf16x8 a[4], b[4];
#pragma unroll
      for (int m = 0; m < 4; m++)
        a[m] = *(const bf16x8*)&As[(wm + m * 16 + lr) * 64 + sl];
#pragma unroll
      for (int n = 0; n < 4; n++)
        b[n] = *(const bf16x8*)&Bs[(wn + n * 16 + lr) * 64 + sl];
#pragma unroll
      for (int m = 0; m < 4; m++)
#pragma unroll
        for (int n = 0; n < 4; n++)
          acc[m][n] = __builtin_amdgcn_mfma_f32_16x16x32_bf16(a[m], b[n], acc[m][n], 0, 0, 0);
    }
    __syncthreads();
  }

  // SwiGLU epilogue: frag pair (2g,2g+1) = (h1,h3), hidden h = ((n0+wn)>>5 + g)*16 + lr
  const int hq = (n0 + wn) >> 5;
#pragma unroll
  for (int g = 0; g < 2; g++) {
    int h = (hq + g) * 16 + lr;
    float b1v = b1[e * HID + h];
    float b3v = b3[e * HID + h];
#pragma unroll
    for (int m = 0; m < 4; m++) {
#pragma unroll
      for (int j = 0; j < 4; j++) {
        int rr = m0 + wm + m * 16 + lk * 4 + j;
        if (rr < ne) {
          float h1 = acc[m][2 * g][j] + b1v;
          float h3 = acc[m][2 * g + 1][j] + b3v;
          float v = h1 * h3;
          h_buf[(size_t)(rs + rr) * HID + h] = f2bf(v / (1.f + expf(-v)));
        }
      }
    }
  }
}

// ============ stage B: 128x128, BK=64, m97 single-buffer 2-barrier, swizzled ============
__global__ __launch_bounds__(256, 3) void ffn_b_kernel(
    const unsigned short* __restrict__ h_buf,
    const unsigned short* __restrict__ W2t,
    const float* __restrict__ b2,
    const int* __restrict__ counts, const int* __restrict__ row_start,
    const int* __restrict__ tp, const int* __restrict__ list,
    const float* __restrict__ topk_w, float* __restrict__ o_buf) {
  __shared__ unsigned short As[128 * 64];
  __shared__ unsigned short Bs[128 * 64];
  const int by = blockIdx.y;
  if (by >= tp[NE]) return;
  int e = 0;
#pragma unroll
  for (int k = 1; k < NE; k++) if (by >= tp[k]) e = k;
  const int ne = counts[e], rs = row_start[e];
  const int m0 = (by - tp[e]) * 128;
  const int n0 = blockIdx.x * 128;

  const int tid = threadIdx.x;
  const int wave = tid >> 6, lane = tid & 63;
  const int lr = lane & 15, lk = lane >> 4;
  const int wm = (wave >> 1) * 64, wn = (wave & 1) * 64;

  const int scs = ((lane & 7) ^ (lane >> 3)) * 8;
  const unsigned short* asrc[4];
  const unsigned short* bsrc[4];
#pragma unroll
  for (int i = 0; i < 4; i++) {
    int sr = (wave * 4 + i) * 8 + (lane >> 3);
    asrc[i] = h_buf + (size_t)(rs + m0 + sr) * HID + scs;   // padded rows, in-bounds
    bsrc[i] = W2t + ((size_t)e * OUTD + n0 + sr) * HID + scs;
  }

  f32x4 acc[4][4];
  const f32x4 zero = {0.f, 0.f, 0.f, 0.f};
#pragma unroll
  for (int m = 0; m < 4; m++)
#pragma unroll
    for (int n = 0; n < 4; n++) acc[m][n] = zero;

  const int sx = lr & 7;

  for (int k0 = 0; k0 < HID; k0 += 64) {
#pragma unroll
    for (int i = 0; i < 4; i++) {
      gload16(asrc[i] + k0, &As[(wave * 4 + i) * 512]);
      gload16(bsrc[i] + k0, &Bs[(wave * 4 + i) * 512]);
    }
    __syncthreads();
#pragma unroll
    for (int kk = 0; kk < 2; kk++) {
      const int sl = ((kk * 4 + lk) ^ sx) * 8;
      bf16x8 a[4], b[4];
#pragma unroll
      for (int m = 0; m < 4; m++)
        a[m] = *(const bf16x8*)&As[(wm + m * 16 + lr) * 64 + sl];
#pragma unroll
      for (int n = 0; n < 4; n++)
        b[n] = *(const bf16x8*)&Bs[(wn + n * 16 + lr) * 64 + sl];
#pragma unroll
      for (int m = 0; m < 4; m++)
#pragma unroll
        for (int n = 0; n < 4; n++)
          acc[m][n] = __builtin_amdgcn_mfma_f32_16x16x32_bf16(a[m], b[n], acc[m][n], 0, 0, 0);
    }
    __syncthreads();
  }

#pragma unroll
  for (int n = 0; n < 4; n++) {
    int col = n0 + wn + n * 16 + lr;
    float b2v = b2[e * OUTD + col];
#pragma unroll
    for (int m = 0; m < 4; m++) {
#pragma unroll
      for (int j = 0; j < 4; j++) {
        int rr = m0 + wm + m * 16 + lk * 4 + j;
        if (rr < ne) {
          int entry = list[rs + rr];
          float w = topk_w[entry];
          o_buf[(size_t)entry * OUTD + col] = w * (acc[m][n][j] + b2v);
        }
      }
    }
  }
}

// ---------------- final: out = (o0 + o1) @ Wf + bf ----------------
__global__ __launch_bounds__(256) void final_kernel(
    const float* __restrict__ o_buf, const unsigned short* __restrict__ Wft,
    const float* __restrict__ bfv, float* __restrict__ out) {
  const int m0 = blockIdx.y * 128, n0 = blockIdx.x * 128;

  __shared__ unsigned short As[128 * 64];
  __shared__ unsigned short Bs[128 * 64];

  const int tid = threadIdx.x;
  const int wave = tid >> 6, lane = tid & 63;
  const int lrow = lane >> 3;
  const int lcol = (lane & 7) * 8;

  const unsigned short* bsrc[4];
#pragma unroll
  for (int i = 0; i < 4; i++) {
    int sr = (wave * 4 + i) * 8 + lrow;
    bsrc[i] = Wft + (size_t)(n0 + sr) * DIM + lcol;
  }

  const int wm = (wave >> 1) * 64, wn = (wave & 1) * 64;
  const int lr = lane & 15, lk = lane >> 4;

  f32x4 acc[4][4];
  const f32x4 zero = {0.f, 0.f, 0.f, 0.f};
#pragma unroll
  for (int m = 0; m < 4; m++)
#pragma unroll
    for (int n = 0; n < 4; n++) acc[m][n] = zero;

  for (int k0 = 0; k0 < DIM; k0 += 64) {
#pragma unroll
    for (int g = 0; g < 8; g++) {
      int idx = g * 256 + tid;
      int r = idx >> 4;
      int c4 = (idx & 15) * 4;
      const float4 v0 = *(const float4*)&o_buf[(size_t)(m0 + r) * 2 * OUTD + k0 + c4];
      const float4 v1 = *(const float4*)&o_buf[(size_t)(m0 + r) * 2 * OUTD + OUTD + k0 + c4];
      ushort4 u;
      u.x = f2bf(v0.x + v1.x); u.y = f2bf(v0.y + v1.y);
      u.z = f2bf(v0.z + v1.z); u.w = f2bf(v0.w + v1.w);
      *(ushort4*)&As[r * 64 + c4] = u;
    }
#pragma unroll
    for (int i = 0; i < 4; i++) gload16(bsrc[i] + k0, &Bs[(wave * 4 + i) * 512]);
    __syncthreads();
#pragma unroll
    for (int kk = 0; kk < 2; kk++) {
      bf16x8 a[4], b[4];
#pragma unroll
      for (int m = 0; m < 4; m++)
        a[m] = *(const bf16x8*)&As[(wm + m * 16 + lr) * 64 + kk * 32 + lk * 8];
#pragma unroll
      for (int n = 0; n < 4; n++)
        b[n] = *(const bf16x8*)&Bs[(wn + n * 16 + lr) * 64 + kk * 32 + lk * 8];
#pragma unroll
      for (int m = 0; m < 4; m++)
#pragma unroll
        for (int n = 0; n < 4; n++)
          acc[m][n] = __builtin_amdgcn_mfma_f32_16x16x32_bf16(a[m], b[n], acc[m][n], 0, 0, 0);
    }
    __syncthreads();
  }

#pragma unroll
  for (int n = 0; n < 4; n++) {
    int col = n0 + wn + n * 16 + lr;
    float bv = bfv[col];
#pragma unroll
    for (int m = 0; m < 4; m++) {
#pragma unroll
      for (int j = 0; j < 4; j++) {
        int r = m0 + wm + m * 16 + lk * 4 + j;
        out[(size_t)r * OUTD + col] = acc[m][n][j] + bv;
      }
    }
  }
}

extern "C" void kernel_launch(void* const* d_in, const int* in_sizes, int n_in,
                              void* d_out, int out_size, void* d_ws, size_t ws_size,
                              hipStream_t stream) {
  const float* X   = (const float*)d_in[0];
  const float* W1  = (const float*)d_in[1];
  const float* b1  = (const float*)d_in[2];
  const float* W3  = (const float*)d_in[3];
  const float* b3  = (const float*)d_in[4];
  const float* W2  = (const float*)d_in[5];
  const float* b2  = (const float*)d_in[6];
  const float* Wg  = (const float*)d_in[7];
  const float* bg  = (const float*)d_in[8];
  const float* Wf  = (const float*)d_in[9];
  const float* bfv = (const float*)d_in[10];
  float* out = (float*)d_out;

  char* p = (char*)d_ws;
  auto alloc = [&](size_t bytes) { char* r = p; p += (bytes + 255) & ~(size_t)255; return r; };
  unsigned short* Xb   = (unsigned short*)alloc((size_t)NTOK * DIM * 2);
  unsigned short* W13t = (unsigned short*)alloc((size_t)NE * 2 * HID * DIM * 2);
  unsigned short* W2t  = (unsigned short*)alloc((size_t)NE * OUTD * HID * 2);
  unsigned short* Wft  = (unsigned short*)alloc((size_t)OUTD * DIM * 2);
  unsigned short* hbuf = (unsigned short*)alloc((size_t)(NTOK * 2 + 256) * HID * 2);
  float* o_buf         = (float*)alloc((size_t)NTOK * 2 * OUTD * 4);
  int* topk_idx        = (int*)alloc(NTOK * 2 * 4);
  float* topk_w        = (float*)alloc(NTOK * 2 * 4);
  int* counts          = (int*)alloc(2 * NE * 4);
  int* cursors         = counts + NE;
  int* row_start       = (int*)alloc(NE * 4);
  int* tp              = (int*)alloc((NE + 1) * 4);
  int* list            = (int*)alloc(NTOK * 2 * 4);

  hipMemsetAsync(counts, 0, 2 * NE * sizeof(int), stream);

  cast_x_kernel<<<(NTOK * DIM / 8 + 255) / 256, 256, 0, stream>>>(X, Xb, NTOK * DIM / 8);
  tcast_i_kernel<<<dim3(HID / 32, DIM / 32, NE), 256, 0, stream>>>(W1, W13t, 0);
  tcast_i_kernel<<<dim3(HID / 32, DIM / 32, NE), 256, 0, stream>>>(W3, W13t, 1);
  tcast_kernel<<<dim3(OUTD / 32, HID / 32, NE), 256, 0, stream>>>(W2, W2t, HID, OUTD);
  tcast_kernel<<<dim3(OUTD / 32, DIM / 32, 1), 256, 0, stream>>>(Wf, Wft, DIM, OUTD);

  gating_kernel<<<NTOK, 64, 0, stream>>>(X, Wg, bg, topk_idx, topk_w, counts);
  finalize_kernel<<<1, 64, 0, stream>>>(counts, row_start, tp);
  scatter_kernel<<<NTOK / 256, 256, 0, stream>>>(topk_idx, row_start, cursors, list);

  // tile-compact grids, BM=128: max sum ceil(ne/128) = 64+7 = 71 -> 72
  ffn_a_kernel<<<dim3(2 * HID / 128, 72), 256, 0, stream>>>(
      Xb, W13t, b1, b3, counts, row_start, tp, list, hbuf);
  ffn_b_kernel<<<dim3(OUTD / 128, 72), 256, 0, stream>>>(
      hbuf, W2t, b2, counts, row_start, tp, list, topk_w, o_buf);
  final_kernel<<<dim3(OUTD / 128, NTOK / 128), 256, 0, stream>>>(o_buf, Wft, bfv, out);
}

// Round 6
// 302.664 us; speedup vs baseline: 2.0287x; 1.4666x over previous
//
#include <hip/hip_runtime.h>

#define DIM  1024
#define HID  2048
#define OUTD 1024
#define NE   8
#define NTOK 4096

using bf16x8 = __attribute__((ext_vector_type(8))) short;
using f32x4  = __attribute__((ext_vector_type(4))) float;

__device__ __forceinline__ unsigned short f2bf(float f) {
  unsigned int u = __builtin_bit_cast(unsigned int, f);
  u += 0x7fff + ((u >> 16) & 1);   // round-to-nearest-even
  return (unsigned short)(u >> 16);
}

__device__ __forceinline__ void gload16(const void* g, void* l) {
  __builtin_amdgcn_global_load_lds(
      (const __attribute__((address_space(1))) void*)g,
      (__attribute__((address_space(3))) void*)l, 16, 0, 0);
}

// ---------------- transpose + cast: in [R][C] fp32 -> out [C][R] bf16 ----------------
__global__ void tcast_kernel(const float* __restrict__ in,
                             unsigned short* __restrict__ out, int R, int C) {
  __shared__ float tile[32][33];
  size_t zo = (size_t)blockIdx.z * R * C;
  int c0 = blockIdx.x * 32, r0 = blockIdx.y * 32;
  int tx = threadIdx.x & 31, ty = threadIdx.x >> 5;
#pragma unroll
  for (int j = 0; j < 4; j++) {
    int r = ty + j * 8;
    tile[r][tx] = in[zo + (size_t)(r0 + r) * C + c0 + tx];
  }
  __syncthreads();
  int c = threadIdx.x >> 3, q = threadIdx.x & 7;
  ushort4 u;
  u.x = f2bf(tile[q * 4 + 0][c]); u.y = f2bf(tile[q * 4 + 1][c]);
  u.z = f2bf(tile[q * 4 + 2][c]); u.w = f2bf(tile[q * 4 + 3][c]);
  *(ushort4*)&out[zo + (size_t)(c0 + c) * R + r0 + q * 4] = u;
}

// ---- transpose+cast W1/W3 [NE][DIM][HID] -> interleaved W13t [NE][2*HID][DIM]
// z = 0..15: e = z&7, s = z>>3 (s=0 -> W1, s=1 -> W3 half)
__global__ void tcast_i_kernel(const float* __restrict__ W1,
                               const float* __restrict__ W3,
                               unsigned short* __restrict__ out) {
  __shared__ float tile[32][33];
  int z = blockIdx.z, e = z & 7, s = z >> 3;
  const float* inp = (s ? W3 : W1) + (size_t)e * DIM * HID;
  unsigned short* op = out + (size_t)e * 2 * HID * DIM;
  int c0 = blockIdx.x * 32, r0 = blockIdx.y * 32;
  int tx = threadIdx.x & 31, ty = threadIdx.x >> 5;
#pragma unroll
  for (int j = 0; j < 4; j++) {
    int r = ty + j * 8;
    tile[r][tx] = inp[(size_t)(r0 + r) * HID + c0 + tx];
  }
  __syncthreads();
  int c = threadIdx.x >> 3, q = threadIdx.x & 7;
  int h = c0 + c;
  int orow = 32 * (h >> 4) + 16 * s + (h & 15);
  ushort4 u;
  u.x = f2bf(tile[q * 4 + 0][c]); u.y = f2bf(tile[q * 4 + 1][c]);
  u.z = f2bf(tile[q * 4 + 2][c]); u.w = f2bf(tile[q * 4 + 3][c]);
  *(ushort4*)&op[(size_t)orow * DIM + r0 + q * 4] = u;
}

// ---------------- gating + fused X cast + per-block histogram ----------------
// 128 blocks x 256 threads; 32 tokens/block (8/wave)
__global__ __launch_bounds__(256) void gating_kernel(
    const float* __restrict__ X, const float* __restrict__ Wg,
    const float* __restrict__ bg, unsigned short* __restrict__ Xb,
    int* __restrict__ topk_pack, float* __restrict__ topk_w,
    int* __restrict__ blkcnt) {
  __shared__ float wgs[NE][DIM];   // transposed gate weights, 32 KB
  __shared__ int hist[NE];
  const int tid = threadIdx.x;
  for (int d = tid; d < DIM; d += 256) {
#pragma unroll
    for (int e = 0; e < NE; e++) wgs[e][d] = Wg[d * NE + e];
  }
  if (tid < NE) hist[tid] = 0;
  __syncthreads();
  const int wave = tid >> 6, lane = tid & 63;
  for (int tk = wave; tk < 32; tk += 4) {
    const int t = blockIdx.x * 32 + tk;
    const float* xr = X + (size_t)t * DIM;
    // fused bf16 cast: lane covers [lane*16, lane*16+16)
    {
      const float4* xp = (const float4*)(xr + lane * 16);
      float4 v0 = xp[0], v1 = xp[1], v2 = xp[2], v3 = xp[3];
      uint4 w0, w1;
      w0.x = f2bf(v0.x) | ((unsigned)f2bf(v0.y) << 16);
      w0.y = f2bf(v0.z) | ((unsigned)f2bf(v0.w) << 16);
      w0.z = f2bf(v1.x) | ((unsigned)f2bf(v1.y) << 16);
      w0.w = f2bf(v1.z) | ((unsigned)f2bf(v1.w) << 16);
      w1.x = f2bf(v2.x) | ((unsigned)f2bf(v2.y) << 16);
      w1.y = f2bf(v2.z) | ((unsigned)f2bf(v2.w) << 16);
      w1.z = f2bf(v3.x) | ((unsigned)f2bf(v3.y) << 16);
      w1.w = f2bf(v3.z) | ((unsigned)f2bf(v3.w) << 16);
      uint4* op = (uint4*)(Xb + (size_t)t * DIM + lane * 16);
      op[0] = w0; op[1] = w1;
    }
    // routing: strided d (2-way LDS alias = free)
    float acc[NE];
#pragma unroll
    for (int e = 0; e < NE; e++) acc[e] = 0.f;
#pragma unroll
    for (int j = 0; j < 16; j++) {
      float xv = xr[lane + j * 64];
#pragma unroll
      for (int e = 0; e < NE; e++) acc[e] += xv * wgs[e][lane + j * 64];
    }
#pragma unroll
    for (int e = 0; e < NE; e++) {
#pragma unroll
      for (int off = 32; off > 0; off >>= 1) acc[e] += __shfl_xor(acc[e], off, 64);
    }
    if (lane == 0) {
      float p[NE];
      float mx = -1e30f;
#pragma unroll
      for (int e = 0; e < NE; e++) { p[e] = acc[e] + bg[e]; mx = fmaxf(mx, p[e]); }
      float s = 0.f;
#pragma unroll
      for (int e = 0; e < NE; e++) { p[e] = expf(p[e] - mx); s += p[e]; }
      float inv = 1.f / s;
#pragma unroll
      for (int e = 0; e < NE; e++) p[e] *= inv;
      int i1 = 0; float v1 = p[0];
#pragma unroll
      for (int e = 1; e < NE; e++) if (p[e] >= v1) { v1 = p[e]; i1 = e; }
      int i2 = (i1 == 0) ? 1 : 0; float v2 = p[i2];
#pragma unroll
      for (int e = 0; e < NE; e++) {
        if (e == i1) continue;
        if (p[e] >= v2 && e != i2) { v2 = p[e]; i2 = e; }
      }
      topk_pack[t] = i1 | (i2 << 4);
      topk_w[t * 2 + 0] = v1; topk_w[t * 2 + 1] = v2;
      atomicAdd(&hist[i1], 1); atomicAdd(&hist[i2], 1);
    }
  }
  __syncthreads();
  if (tid < NE) blkcnt[blockIdx.x * NE + tid] = hist[tid];
}

// ---------------- prefix: totals, row_start, tp (BM=128), per-block bases ----------------
__global__ void prefix_kernel(const int* __restrict__ blkcnt, int* __restrict__ counts,
                              int* __restrict__ row_start, int* __restrict__ tp,
                              int* __restrict__ base) {
  const int lane = threadIdx.x;  // 64
  int tot[NE];
#pragma unroll
  for (int e = 0; e < NE; e++) {
    int s = blkcnt[lane * NE + e] + blkcnt[(lane + 64) * NE + e];
#pragma unroll
    for (int off = 32; off > 0; off >>= 1) s += __shfl_xor(s, off, 64);
    tot[e] = s;
  }
  int rsv[NE]; int s = 0, t = 0;
#pragma unroll
  for (int e = 0; e < NE; e++) {
    rsv[e] = s;
    if (lane == e) { counts[e] = tot[e]; row_start[e] = s; }
    if (lane == e) tp[e] = t;
    s += tot[e]; t += (tot[e] + 127) >> 7;
  }
  if (lane == 0) tp[NE] = t;
#pragma unroll
  for (int e = 0; e < NE; e++) {
    int c0 = blkcnt[(2 * lane) * NE + e], c1 = blkcnt[(2 * lane + 1) * NE + e];
    int s2 = c0 + c1, scan = s2;
#pragma unroll
    for (int off = 1; off < 64; off <<= 1) {
      int v = __shfl_up(scan, off, 64);
      if (lane >= off) scan += v;
    }
    int excl = scan - s2 + rsv[e];
    base[(2 * lane) * NE + e] = excl;
    base[(2 * lane + 1) * NE + e] = excl + c0;
  }
}

// ---------------- scatter: LDS cursors per block ----------------
__global__ void scatter_kernel(const int* __restrict__ topk_pack, const int* __restrict__ base,
                               int* __restrict__ list) {
  __shared__ int lofs[NE];
  const int blk = blockIdx.x, tid = threadIdx.x;   // 64 threads, 32 tokens
  if (tid < NE) lofs[tid] = base[blk * NE + tid];
  __syncthreads();
  if (tid < 32) {
    int t = blk * 32 + tid;
    int pk = topk_pack[t];
    int e1 = pk & 15, e2 = (pk >> 4) & 15;
    int p1 = atomicAdd(&lofs[e1], 1);
    list[p1] = t << 1;
    int p2 = atomicAdd(&lofs[e2], 1);
    list[p2] = (t << 1) | 1;
  }
}

// ============ stage A: 128x128, m97 loop, XCD-locality remap (8m x 4n per XCD) ============
__global__ __launch_bounds__(256, 3) void ffn_a_kernel(
    const unsigned short* __restrict__ Xb,
    const unsigned short* __restrict__ W13t,
    const float* __restrict__ b1, const float* __restrict__ b3,
    const int* __restrict__ counts, const int* __restrict__ row_start,
    const int* __restrict__ tp, const int* __restrict__ list,
    unsigned short* __restrict__ h_buf) {
  __shared__ unsigned short As[128 * 64];
  __shared__ unsigned short Bs[128 * 64];
  // bid -> (by, bx): XCD = bid&7 owns n-cols [4*xcd,4*xcd+4); inner order: 9 groups of 8m x 4n
  const int bid = blockIdx.x;
  const int xcd = bid & 7, r = bid >> 3;
  const int grp = r >> 5, rr2 = r & 31;
  const int by = grp * 8 + (rr2 & 7);
  const int bx = xcd * 4 + (rr2 >> 3);
  if (by >= tp[NE]) return;
  int e = 0;
#pragma unroll
  for (int k = 1; k < NE; k++) if (by >= tp[k]) e = k;
  const int ne = counts[e], rs = row_start[e];
  const int m0 = (by - tp[e]) * 128;
  const int n0 = bx * 128;

  const int tid = threadIdx.x;
  const int wave = tid >> 6, lane = tid & 63;
  const int lr = lane & 15, lk = lane >> 4;
  const int wm = (wave >> 1) * 64, wn = (wave & 1) * 64;

  const int scs = ((lane & 7) ^ (lane >> 3)) * 8;   // inverse-swizzled source col
  const unsigned short* asrc[4];
  const unsigned short* bsrc[4];
#pragma unroll
  for (int i = 0; i < 4; i++) {
    int sr = (wave * 4 + i) * 8 + (lane >> 3);
    int rr = m0 + sr; if (rr >= ne) rr = m0;
    int tok = list[rs + rr] >> 1;
    asrc[i] = Xb + (size_t)tok * DIM + scs;
    bsrc[i] = W13t + ((size_t)e * 2 * HID + n0 + sr) * DIM + scs;
  }

  f32x4 acc[4][4];
  const f32x4 zero = {0.f, 0.f, 0.f, 0.f};
#pragma unroll
  for (int m = 0; m < 4; m++)
#pragma unroll
    for (int n = 0; n < 4; n++) acc[m][n] = zero;

  const int sx = lr & 7;

  for (int k0 = 0; k0 < DIM; k0 += 64) {
#pragma unroll
    for (int i = 0; i < 4; i++) {
      gload16(asrc[i] + k0, &As[(wave * 4 + i) * 512]);
      gload16(bsrc[i] + k0, &Bs[(wave * 4 + i) * 512]);
    }
    __syncthreads();
#pragma unroll
    for (int kk = 0; kk < 2; kk++) {
      const int sl = ((kk * 4 + lk) ^ sx) * 8;
      bf16x8 a[4], b[4];
#pragma unroll
      for (int m = 0; m < 4; m++)
        a[m] = *(const bf16x8*)&As[(wm + m * 16 + lr) * 64 + sl];
#pragma unroll
      for (int n = 0; n < 4; n++)
        b[n] = *(const bf16x8*)&Bs[(wn + n * 16 + lr) * 64 + sl];
#pragma unroll
      for (int m = 0; m < 4; m++)
#pragma unroll
        for (int n = 0; n < 4; n++)
          acc[m][n] = __builtin_amdgcn_mfma_f32_16x16x32_bf16(a[m], b[n], acc[m][n], 0, 0, 0);
    }
    __syncthreads();
  }

  const int hq = (n0 + wn) >> 5;
#pragma unroll
  for (int g = 0; g < 2; g++) {
    int h = (hq + g) * 16 + lr;
    float b1v = b1[e * HID + h];
    float b3v = b3[e * HID + h];
#pragma unroll
    for (int m = 0; m < 4; m++) {
#pragma unroll
      for (int j = 0; j < 4; j++) {
        int rr = m0 + wm + m * 16 + lk * 4 + j;
        if (rr < ne) {
          float h1 = acc[m][2 * g][j] + b1v;
          float h3 = acc[m][2 * g + 1][j] + b3v;
          float v = h1 * h3;
          h_buf[(size_t)(rs + rr) * HID + h] = f2bf(v / (1.f + expf(-v)));
        }
      }
    }
  }
}

// ============ stage B: 128x128, m97 loop, XCD-locality remap (9m-chunk, 3m x 8n groups) ============
__global__ __launch_bounds__(256, 3) void ffn_b_kernel(
    const unsigned short* __restrict__ h_buf,
    const unsigned short* __restrict__ W2t,
    const float* __restrict__ b2,
    const int* __restrict__ counts, const int* __restrict__ row_start,
    const int* __restrict__ tp, const int* __restrict__ list,
    const float* __restrict__ topk_w, float* __restrict__ o_buf) {
  __shared__ unsigned short As[128 * 64];
  __shared__ unsigned short Bs[128 * 64];
  // bid -> (by, bx): XCD owns m-rows [9*xcd, 9*xcd+9); inner: 3 groups of {n(8) x m(3)}
  const int bid = blockIdx.x;
  const int xcd = bid & 7, r = bid >> 3;
  const int grp = r / 24, rr2 = r % 24;
  const int by = xcd * 9 + grp * 3 + (rr2 % 3);
  const int bx = rr2 / 3;
  if (by >= tp[NE]) return;
  int e = 0;
#pragma unroll
  for (int k = 1; k < NE; k++) if (by >= tp[k]) e = k;
  const int ne = counts[e], rs = row_start[e];
  const int m0 = (by - tp[e]) * 128;
  const int n0 = bx * 128;

  const int tid = threadIdx.x;
  const int wave = tid >> 6, lane = tid & 63;
  const int lr = lane & 15, lk = lane >> 4;
  const int wm = (wave >> 1) * 64, wn = (wave & 1) * 64;

  const int scs = ((lane & 7) ^ (lane >> 3)) * 8;
  const unsigned short* asrc[4];
  const unsigned short* bsrc[4];
#pragma unroll
  for (int i = 0; i < 4; i++) {
    int sr = (wave * 4 + i) * 8 + (lane >> 3);
    asrc[i] = h_buf + (size_t)(rs + m0 + sr) * HID + scs;   // padded rows, in-bounds
    bsrc[i] = W2t + ((size_t)e * OUTD + n0 + sr) * HID + scs;
  }

  f32x4 acc[4][4];
  const f32x4 zero = {0.f, 0.f, 0.f, 0.f};
#pragma unroll
  for (int m = 0; m < 4; m++)
#pragma unroll
    for (int n = 0; n < 4; n++) acc[m][n] = zero;

  const int sx = lr & 7;

  for (int k0 = 0; k0 < HID; k0 += 64) {
#pragma unroll
    for (int i = 0; i < 4; i++) {
      gload16(asrc[i] + k0, &As[(wave * 4 + i) * 512]);
      gload16(bsrc[i] + k0, &Bs[(wave * 4 + i) * 512]);
    }
    __syncthreads();
#pragma unroll
    for (int kk = 0; kk < 2; kk++) {
      const int sl = ((kk * 4 + lk) ^ sx) * 8;
      bf16x8 a[4], b[4];
#pragma unroll
      for (int m = 0; m < 4; m++)
        a[m] = *(const bf16x8*)&As[(wm + m * 16 + lr) * 64 + sl];
#pragma unroll
      for (int n = 0; n < 4; n++)
        b[n] = *(const bf16x8*)&Bs[(wn + n * 16 + lr) * 64 + sl];
#pragma unroll
      for (int m = 0; m < 4; m++)
#pragma unroll
        for (int n = 0; n < 4; n++)
          acc[m][n] = __builtin_amdgcn_mfma_f32_16x16x32_bf16(a[m], b[n], acc[m][n], 0, 0, 0);
    }
    __syncthreads();
  }

#pragma unroll
  for (int n = 0; n < 4; n++) {
    int col = n0 + wn + n * 16 + lr;
    float b2v = b2[e * OUTD + col];
#pragma unroll
    for (int m = 0; m < 4; m++) {
#pragma unroll
      for (int j = 0; j < 4; j++) {
        int rr = m0 + wm + m * 16 + lk * 4 + j;
        if (rr < ne) {
          int entry = list[rs + rr];
          float w = topk_w[entry];
          o_buf[(size_t)entry * OUTD + col] = w * (acc[m][n][j] + b2v);
        }
      }
    }
  }
}

// ---------------- final: out = (o0 + o1) @ Wf + bf ----------------
__global__ __launch_bounds__(256) void final_kernel(
    const float* __restrict__ o_buf, const unsigned short* __restrict__ Wft,
    const float* __restrict__ bfv, float* __restrict__ out) {
  const int m0 = blockIdx.y * 128, n0 = blockIdx.x * 128;

  __shared__ unsigned short As[128 * 64];
  __shared__ unsigned short Bs[128 * 64];

  const int tid = threadIdx.x;
  const int wave = tid >> 6, lane = tid & 63;
  const int lrow = lane >> 3;
  const int lcol = (lane & 7) * 8;

  const unsigned short* bsrc[4];
#pragma unroll
  for (int i = 0; i < 4; i++) {
    int sr = (wave * 4 + i) * 8 + lrow;
    bsrc[i] = Wft + (size_t)(n0 + sr) * DIM + lcol;
  }

  const int wm = (wave >> 1) * 64, wn = (wave & 1) * 64;
  const int lr = lane & 15, lk = lane >> 4;

  f32x4 acc[4][4];
  const f32x4 zero = {0.f, 0.f, 0.f, 0.f};
#pragma unroll
  for (int m = 0; m < 4; m++)
#pragma unroll
    for (int n = 0; n < 4; n++) acc[m][n] = zero;

  for (int k0 = 0; k0 < DIM; k0 += 64) {
#pragma unroll
    for (int g = 0; g < 8; g++) {
      int idx = g * 256 + tid;
      int r = idx >> 4;
      int c4 = (idx & 15) * 4;
      const float4 v0 = *(const float4*)&o_buf[(size_t)(m0 + r) * 2 * OUTD + k0 + c4];
      const float4 v1 = *(const float4*)&o_buf[(size_t)(m0 + r) * 2 * OUTD + OUTD + k0 + c4];
      ushort4 u;
      u.x = f2bf(v0.x + v1.x); u.y = f2bf(v0.y + v1.y);
      u.z = f2bf(v0.z + v1.z); u.w = f2bf(v0.w + v1.w);
      *(ushort4*)&As[r * 64 + c4] = u;
    }
#pragma unroll
    for (int i = 0; i < 4; i++) gload16(bsrc[i] + k0, &Bs[(wave * 4 + i) * 512]);
    __syncthreads();
#pragma unroll
    for (int kk = 0; kk < 2; kk++) {
      bf16x8 a[4], b[4];
#pragma unroll
      for (int m = 0; m < 4; m++)
        a[m] = *(const bf16x8*)&As[(wm + m * 16 + lr) * 64 + kk * 32 + lk * 8];
#pragma unroll
      for (int n = 0; n < 4; n++)
        b[n] = *(const bf16x8*)&Bs[(wn + n * 16 + lr) * 64 + kk * 32 + lk * 8];
#pragma unroll
      for (int m = 0; m < 4; m++)
#pragma unroll
        for (int n = 0; n < 4; n++)
          acc[m][n] = __builtin_amdgcn_mfma_f32_16x16x32_bf16(a[m], b[n], acc[m][n], 0, 0, 0);
    }
    __syncthreads();
  }

#pragma unroll
  for (int n = 0; n < 4; n++) {
    int col = n0 + wn + n * 16 + lr;
    float bv = bfv[col];
#pragma unroll
    for (int m = 0; m < 4; m++) {
#pragma unroll
      for (int j = 0; j < 4; j++) {
        int r = m0 + wm + m * 16 + lk * 4 + j;
        out[(size_t)r * OUTD + col] = acc[m][n][j] + bv;
      }
    }
  }
}

extern "C" void kernel_launch(void* const* d_in, const int* in_sizes, int n_in,
                              void* d_out, int out_size, void* d_ws, size_t ws_size,
                              hipStream_t stream) {
  const float* X   = (const float*)d_in[0];
  const float* W1  = (const float*)d_in[1];
  const float* b1  = (const float*)d_in[2];
  const float* W3  = (const float*)d_in[3];
  const float* b3  = (const float*)d_in[4];
  const float* W2  = (const float*)d_in[5];
  const float* b2  = (const float*)d_in[6];
  const float* Wg  = (const float*)d_in[7];
  const float* bg  = (const float*)d_in[8];
  const float* Wf  = (const float*)d_in[9];
  const float* bfv = (const float*)d_in[10];
  float* out = (float*)d_out;

  char* p = (char*)d_ws;
  auto alloc = [&](size_t bytes) { char* r = p; p += (bytes + 255) & ~(size_t)255; return r; };
  unsigned short* Xb   = (unsigned short*)alloc((size_t)NTOK * DIM * 2);
  unsigned short* W13t = (unsigned short*)alloc((size_t)NE * 2 * HID * DIM * 2);
  unsigned short* W2t  = (unsigned short*)alloc((size_t)NE * OUTD * HID * 2);
  unsigned short* Wft  = (unsigned short*)alloc((size_t)OUTD * DIM * 2);
  unsigned short* hbuf = (unsigned short*)alloc((size_t)(NTOK * 2 + 256) * HID * 2);
  float* o_buf         = (float*)alloc((size_t)NTOK * 2 * OUTD * 4);
  int* topk_pack       = (int*)alloc(NTOK * 4);
  float* topk_w        = (float*)alloc(NTOK * 2 * 4);
  int* counts          = (int*)alloc(NE * 4);
  int* row_start       = (int*)alloc(NE * 4);
  int* tp              = (int*)alloc((NE + 1) * 4);
  int* blkcnt          = (int*)alloc(128 * NE * 4);
  int* base            = (int*)alloc(128 * NE * 4);
  int* list            = (int*)alloc(NTOK * 2 * 4);

  gating_kernel<<<128, 256, 0, stream>>>(X, Wg, bg, Xb, topk_pack, topk_w, blkcnt);
  tcast_i_kernel<<<dim3(HID / 32, DIM / 32, 16), 256, 0, stream>>>(W1, W3, W13t);
  tcast_kernel<<<dim3(OUTD / 32, HID / 32, NE), 256, 0, stream>>>(W2, W2t, HID, OUTD);
  tcast_kernel<<<dim3(OUTD / 32, DIM / 32, 1), 256, 0, stream>>>(Wf, Wft, DIM, OUTD);

  prefix_kernel<<<1, 64, 0, stream>>>(blkcnt, counts, row_start, tp, base);
  scatter_kernel<<<128, 64, 0, stream>>>(topk_pack, base, list);

  ffn_a_kernel<<<2304, 256, 0, stream>>>(
      Xb, W13t, b1, b3, counts, row_start, tp, list, hbuf);
  ffn_b_kernel<<<576, 256, 0, stream>>>(
      hbuf, W2t, b2, counts, row_start, tp, list, topk_w, o_buf);
  final_kernel<<<dim3(OUTD / 128, NTOK / 128), 256, 0, stream>>>(o_buf, Wft, bfv, out);
}